// Round 4
// baseline (2693.846 us; speedup 1.0000x reference)
//
#include <hip/hip_runtime.h>
#include <math.h>

// ---------------- types ----------------
typedef _Float16 f16;
typedef _Float16 f16x8 __attribute__((ext_vector_type(8)));
typedef float f32x4 __attribute__((ext_vector_type(4)));

#define DEV static __device__ __forceinline__

DEV float sigm(float x)  { return 1.0f / (1.0f + __expf(-x)); }
DEV float tanhfast(float x) { return 2.0f / (1.0f + __expf(-2.0f * x)) - 1.0f; }

// async global->LDS, 16B per lane (dest must be wave-uniform base + lane*16)
DEV void gld16(const void* g, void* l) {
  __builtin_amdgcn_global_load_lds((const __attribute__((address_space(1))) void*)g,
                                   (__attribute__((address_space(3))) void*)l, 16, 0, 0);
}

// ---------------- problem constants ----------------
// B=256 V=50 N=32 D=128 H=384 L=12 CS=10 ND=4096 G=1560 OUT=128
#define GP 1664   // padded G (13*128) — XK gemm N and XKh row stride
#define XOS 1576  // xo LDS row stride f16 (788 dw, %32=20 -> <=2-way banking)
#define HXS 416   // hext LDS row stride f16 (208 dw, %32=16 -> m97-pattern 2-way free)
#define KH 3840   // H*CS (conv gemm K)
#define KO 19200  // V*H  (out gemm K)

// ---------------- workspace layout (bytes) ----------------
static constexpr size_t OFF_X     = 0;                       // xf 104857600; lh aliases; opart aliases
static constexpr size_t OFF_LH    = 0;
static constexpr size_t OFF_OPART = 0;
static constexpr size_t OFF_WK    = 104857600;               // 13631488
static constexpr size_t OFF_XK    = OFF_WK + 13631488;       // XKh f16 12800*1664*2 = 42598400
// aliases of the XK region (XKh dead after k_recur; swp/rwp2/sbp live beyond 42.6MB mark):
static constexpr size_t OFF_MLH   = OFF_XK;                  // mlh_h f16 9830400
static constexpr size_t OFF_S1    = OFF_XK + 9830400;        // s1h f16 3276800
static constexpr size_t OFF_TH    = OFF_XK + 13107200;       // theme f32 19660800
static constexpr size_t OFF_CV    = OFF_XK + 32768000;       // conv f32 19660800 (ends +52428800)
static constexpr size_t OFF_SWP   = OFF_XK + 52428800;       // swp f16 98304 (> XKh end)
static constexpr size_t OFF_RWP2  = OFF_XK + 52527104;       // rwp2 f16 98304
static constexpr size_t OFF_SBP   = OFF_XK + 52625408;       // sbp f32 512
static constexpr size_t OFF_RW    = OFF_XK + 85196800;       // RW384 f16 1664*384*2 = 1277952
static constexpr size_t OFF_SV    = OFF_RW + 1277952;        // Sv f32 1664*4 = 6656
static constexpr size_t OFF_BIASC = OFF_RW + 1384448;        // 8192
static constexpr size_t OFF_HALL  = OFF_BIASC + 8192;        // h_all f32 19660800
static constexpr size_t OFF_LD    = OFF_HALL + 19660800;     // 512000
static constexpr size_t OFF_WC2   = OFF_LD + 512000;         // 2949120
static constexpr size_t OFF_RNN   = OFF_WC2 + 2949120;       // 9830400
static constexpr size_t OFF_OUTW  = OFF_RNN + 9830400;       // 4915200

// ---------------- kernels ----------------

// embedding gather -> x_f16 (12800 x 4096), 8 halfs / thread
__global__ __launch_bounds__(256) void k_gather(const int* __restrict__ ids,
                                                const float* __restrict__ embed,
                                                f16* __restrict__ xf) {
  int i = blockIdx.x * 256 + threadIdx.x;     // 12800*512 total
  int row = i >> 9;
  int c8  = i & 511;
  int n = c8 >> 4;
  int d = (c8 & 15) << 3;
  int id = ids[row * 32 + n];
  const float* e = embed + (long)id * 128 + d;
  float4 a = *(const float4*)e;
  float4 b = *(const float4*)(e + 4);
  f16x8 o;
  o[0]=(f16)a.x; o[1]=(f16)a.y; o[2]=(f16)a.z; o[3]=(f16)a.w;
  o[4]=(f16)b.x; o[5]=(f16)b.y; o[6]=(f16)b.z; o[7]=(f16)b.w;
  *(f16x8*)(xf + ((long)row << 12) + (c8 << 3)) = o;
}

// kernel_w (1560 x 4097) -> Wk_f16 (1664 x 4096, zero-padded rows); biasc = kb+rb (padded 1664)
__global__ __launch_bounds__(256) void k_prep_wk(const float* __restrict__ kw,
                                                 const float* __restrict__ kb,
                                                 const float* __restrict__ rb,
                                                 f16* __restrict__ Wk,
                                                 float* __restrict__ biasc) {
  long i = (long)blockIdx.x * 256 + threadIdx.x;
  if (i < 1664L * 4096) {
    int nn = (int)(i >> 12);
    int k  = (int)(i & 4095);
    float v = (nn < 1560) ? kw[(long)nn * 4097 + k] : 0.0f;
    Wk[i] = (f16)v;
  }
  if (i < 1664) biasc[i] = (i < 1560) ? (kb[i] + rb[i]) : 0.0f;
}

// rec_w (1560 x 385) -> RW384 f16 (1664 x 384, zero-padded); Sv[n] = rec_w[n][384] + kernel_w[n][4096]
__global__ __launch_bounds__(256) void k_prep_rw(const float* __restrict__ rw,
                                                 const float* __restrict__ kw,
                                                 f16* __restrict__ RW,
                                                 float* __restrict__ Sv) {
  long i = (long)blockIdx.x * 256 + threadIdx.x;
  if (i < 1664L * 384) {
    int nn = (int)(i / 384);
    int k  = (int)(i - (long)nn * 384);
    RW[i] = (f16)((nn < 1560) ? rw[(long)nn * 385 + k] : 0.0f);
  }
  if (i < 1664)
    Sv[i] = (i < 1560) ? (rw[(long)i * 385 + 384] + kw[(long)i * 4097 + 4096]) : 0.0f;
}

// conv_w (384,384,10) -> Wc2_f16[o][j*384+h]
__global__ __launch_bounds__(256) void k_prep_wc(const float* __restrict__ cw,
                                                 f16* __restrict__ Wc2) {
  int i = blockIdx.x * 256 + threadIdx.x;     // 384*3840
  if (i >= 384 * 3840) return;
  int o = i / 3840;
  int c = i - o * 3840;
  int j = c / 384;
  int h = c - j * 384;
  Wc2[i] = (f16)cw[((long)o * 384 + h) * 10 + j];
}

// scale_w (64,384)->swp(128,384,f16,zero-pad rows); scale_b->sbp(128); rescale_w(384,64)->rwp2(384,128,zero-pad cols)
__global__ __launch_bounds__(256) void k_prep_scale(const float* __restrict__ sw,
                                                    const float* __restrict__ sb,
                                                    const float* __restrict__ rw2,
                                                    f16* __restrict__ swp,
                                                    float* __restrict__ sbp,
                                                    f16* __restrict__ rwp2) {
  int i = blockIdx.x * 256 + threadIdx.x;   // 49152
  if (i < 128 * 384) {
    int o = i / 384, k = i - o * 384;
    swp[i] = (f16)((o < 64) ? sw[o * 384 + k] : 0.0f);
    int o2 = i >> 7, k2 = i & 127;
    rwp2[i] = (f16)((k2 < 64) ? rw2[o2 * 64 + k2] : 0.0f);
  }
  if (i < 128) sbp[i] = (i < 64) ? sb[i] : 0.0f;
}

// generic fp32 -> f16 convert
__global__ __launch_bounds__(256) void k_cvt(const float* __restrict__ src,
                                             f16* __restrict__ dst, long n) {
  long i = (long)blockIdx.x * 256 + threadIdx.x;
  if (i < n) dst[i] = (f16)src[i];
}

// C = A(M x K) * W(N x K)^T (+bias[col]); m97-style global_load_lds staging.
// grid.z splits K (writes partials at z*M*N). act: 0=f32, 1=f16, 2=relu->f16, 3=sigmoid->f32.
__global__ __launch_bounds__(256) void k_gemm_bt(const f16* __restrict__ A,
                                                 const f16* __restrict__ W,
                                                 void* __restrict__ Cv,
                                                 const float* __restrict__ bias,
                                                 int N, int K, int kLen, int act) {
  __shared__ __align__(16) f16 As[128 * 32];   // unpadded: global_load_lds needs lane-contiguous dest
  __shared__ __align__(16) f16 Bs[128 * 32];
  const int tid = threadIdx.x;
  const long rowA0 = (long)blockIdx.x * 128;
  const long rowB0 = (long)blockIdx.y * 128;
  const long ks = (long)blockIdx.z * kLen;
  const long zoff = (long)blockIdx.z * ((long)gridDim.x * 128 * N);
  const int w = tid >> 6, lane = tid & 63;
  const int q = lane >> 4, r16 = lane & 15;
  const int wr = w >> 1, wc = w & 1;
  f32x4 acc[4][4] = {};
  const int srow = tid >> 2;
  const int scol = (tid & 3) * 8;
  const f16* gA0 = A + (rowA0 + srow) * (long)K + ks + scol;
  const f16* gA1 = gA0 + 64L * K;
  const f16* gB0 = W + (rowB0 + srow) * (long)K + ks + scol;
  const f16* gB1 = gB0 + 64L * K;
  f16* lA = As + tid * 8;
  f16* lB = Bs + tid * 8;
  for (int k0 = 0; k0 < kLen; k0 += 32) {
    __syncthreads();
    gld16(gA0 + k0, lA);
    gld16(gA1 + k0, lA + 2048);
    gld16(gB0 + k0, lB);
    gld16(gB1 + k0, lB + 2048);
    __syncthreads();
    f16x8 af[4], bfr[4];
#pragma unroll
    for (int i = 0; i < 4; i++) {
      af[i]  = *(const f16x8*)&As[(wr * 64 + i * 16 + r16) * 32 + q * 8];
      bfr[i] = *(const f16x8*)&Bs[(wc * 64 + i * 16 + r16) * 32 + q * 8];
    }
#pragma unroll
    for (int i = 0; i < 4; i++)
#pragma unroll
      for (int j = 0; j < 4; j++)
        acc[i][j] = __builtin_amdgcn_mfma_f32_16x16x32_f16(af[i], bfr[j], acc[i][j], 0, 0, 0);
  }
#pragma unroll
  for (int i = 0; i < 4; i++)
#pragma unroll
    for (int j = 0; j < 4; j++) {
      long row = rowA0 + wr * 64 + i * 16 + q * 4;
      long col = rowB0 + wc * 64 + j * 16 + r16;
      float bv = bias ? bias[col] : 0.0f;
#pragma unroll
      for (int r = 0; r < 4; r++) {
        float v = acc[i][j][r] + bv;
        long off = (row + r) * (long)N + col + zoff;
        if (act == 0)      ((float*)Cv)[off] = v;
        else if (act == 1) ((f16*)Cv)[off]   = (f16)v;
        else if (act == 2) ((f16*)Cv)[off]   = (f16)fmaxf(v, 0.0f);
        else               ((float*)Cv)[off] = sigm(v);
      }
    }
}

// weights-stationary sequential scan: 16 blocks x 16 batches x 1024 threads (16 waves, 4/SIMD).
// Each wave holds 6-7 RW tiles (16 cols x 384 K, f16 frags) in REGISTERS for all 50 steps.
// xo[b][n] = h@RW^T + XKh (pre-biased) + tv_b * Sv[n].
__global__ __launch_bounds__(1024, 1) __attribute__((amdgpu_waves_per_eu(4, 4)))
void k_recur(const f16* __restrict__ XKh,    // (12800,1664) f16, bias folded
             const f16* __restrict__ RW,     // (1664,384) f16
             const float* __restrict__ Sv,   // (1664)
             const float* __restrict__ timep,
             float* __restrict__ h_all,      // (50,256,384)
             float* __restrict__ dists) {    // (50,256)
  __shared__ f16 xo[16 * XOS];                 // 50432 B
  __shared__ __align__(16) f16 hext[16 * HXS]; // 13312 B
  __shared__ float tvs[16];                    // total 63808 B
  const int tid = threadIdx.x;
  const int b0 = blockIdx.x * 16;
  const int w = tid >> 6, lane = tid & 63;
  const int q = lane >> 4, r16 = lane & 15;
  const int cnt = (w < 2) ? 7 : 6;             // tiles w+16k, k<cnt (98 tiles total, cols 0..1567)
  for (int i = tid; i < 16 * HXS; i += 1024) hext[i] = (f16)0;
  if (tid < 16) tvs[tid] = timep[(b0 + tid) * 50];

  // ---- load stationary weights (once) ----
  f16x8 Wf[7][12];
  float Sr[7];
#pragma unroll
  for (int k = 0; k < 7; k++) if (k < cnt) {
    const int tile = w + 16 * k;
    const f16* wr = RW + (long)(tile * 16 + r16) * 384 + q * 8;
#pragma unroll
    for (int f = 0; f < 12; f++) Wf[k][f] = *(const f16x8*)(wr + f * 32);
    Sr[k] = Sv[tile * 16 + r16];
  }

  const int gm = tid >> 5, gch = tid & 31;     // gate mapping (threads 0..511)
  float creg[12] = {};

  for (int t = 0; t < 50; t++) {
    // XK prefetch for this step (independent of hext) — latency hides under barrier+MFMA
    f16 xk[7][4];
    const f16* xkb = XKh + ((long)(b0 + q * 4) * 50 + t) * GP + r16;
#pragma unroll
    for (int k = 0; k < 7; k++) if (k < cnt) {
#pragma unroll
      for (int r = 0; r < 4; r++)
        xk[k][r] = xkb[(long)r * 50 * GP + (w + 16 * k) * 16];
    }
    __syncthreads();   // hext/tvs ready; xo consumers of t-1 done
    f16x8 af[12];
    const f16* hrow = hext + r16 * HXS + q * 8;
#pragma unroll
    for (int f = 0; f < 12; f++) af[f] = *(const f16x8*)(hrow + f * 32);
    float tvr[4];
#pragma unroll
    for (int r = 0; r < 4; r++) tvr[r] = tvs[q * 4 + r];
#pragma unroll
    for (int k = 0; k < 7; k++) if (k < cnt) {
      f32x4 a0 = {};
#pragma unroll
      for (int f = 0; f < 12; f++)
        a0 = __builtin_amdgcn_mfma_f32_16x16x32_f16(af[f], Wf[k][f], a0, 0, 0, 0);
      const int c0 = (w + 16 * k) * 16 + r16;
#pragma unroll
      for (int r = 0; r < 4; r++)
        xo[(q * 4 + r) * XOS + c0] = (f16)(a0[r] + (float)xk[k][r] + tvr[r] * Sr[k]);
    }
    __syncthreads();   // xo ready
    if (w < 8) {       // gates: thread = (batch gm, channel gch); waves 8..15 skip to barrier
      const f16* xom = xo + gm * XOS;
      const int b = b0 + gm;
      float fm[12], im[12];
      {
        float v1[12], v2[12], mx1 = -1e30f, mx2 = -1e30f;
#pragma unroll
        for (int l = 0; l < 12; l++) {
          v1[l] = (float)xom[l];      mx1 = fmaxf(mx1, v1[l]);
          v2[l] = (float)xom[12 + l]; mx2 = fmaxf(mx2, v2[l]);
        }
        float s1 = 0.0f, s2 = 0.0f;
#pragma unroll
        for (int l = 0; l < 12; l++) {
          v1[l] = __expf(v1[l] - mx1); s1 += v1[l];
          v2[l] = __expf(v2[l] - mx2); s2 += v2[l];
        }
        float i1 = 1.0f / s1, i2 = 1.0f / s2, c1 = 0.0f, c2 = 0.0f;
#pragma unroll
        for (int l = 0; l < 12; l++) { c1 += v1[l]; fm[l] = c1 * i1; }
#pragma unroll
        for (int l = 11; l >= 0; l--) { c2 += v2[l]; im[l] = c2 * i2; }
      }
      if (gch == 0) {
        float ds = 0.0f;
#pragma unroll
        for (int l = 0; l < 12; l++) ds += fm[l];
        dists[t * 256 + b] = 1.0f - ds * (1.0f / 12.0f);
      }
      float* hdst = h_all + ((long)t * 256 + b) * 384;
#pragma unroll
      for (int l = 0; l < 12; l++) {
        float fv = sigm((float)xom[24 + l * 32 + gch]);
        float iv = sigm((float)xom[24 + (12 + l) * 32 + gch]);
        float og = sigm((float)xom[24 + (24 + l) * 32 + gch]);
        float ci = tanhfast((float)xom[24 + (36 + l) * 32 + gch]);
        float fmv = fm[l], imv = im[l], ov = fmv * imv;
        float cn = ov * (fv * creg[l] + iv * ci) + (fmv - ov) * creg[l] + (imv - ov) * ci;
        creg[l] = cn;
        float hv = og * tanhfast(cn);
        hdst[l * 32 + gch] = hv;
        hext[gm * HXS + l * 32 + gch] = (f16)hv;
      }
      if (gch == 1 && t < 49) tvs[gm] = timep[b * 50 + t + 1];
    }
  }
}

// ld[b,t,:] = softmax_j(cumsum_j dist[t-9+j])
__global__ __launch_bounds__(256) void k_ld(const float* __restrict__ dists,
                                            float* __restrict__ ld) {
  int i = blockIdx.x * 256 + threadIdx.x;
  if (i >= 12800) return;
  int b = i / 50, t = i - b * 50;
  float v[10];
  float cum = 0.0f, mx = -1e30f;
#pragma unroll
  for (int j = 0; j < 10; j++) {
    int s = t - 9 + j;
    float d = (s >= 0) ? dists[s * 256 + b] : 0.0f;
    cum += d; v[j] = cum; mx = fmaxf(mx, cum);
  }
  float sum = 0.0f;
#pragma unroll
  for (int j = 0; j < 10; j++) { v[j] = __expf(v[j] - mx); sum += v[j]; }
  float inv = 1.0f / sum;
#pragma unroll
  for (int j = 0; j < 10; j++) ld[i * 10 + j] = v[j] * inv;
}

// lh_f16[(b,t)][j*384+h] = ld[b,t,j] * h_{t-9+j}[b,h]
__global__ __launch_bounds__(256) void k_lh(const float* __restrict__ ld,
                                            const float* __restrict__ h_all,
                                            f16* __restrict__ lh) {
  int i = blockIdx.x * 256 + threadIdx.x;   // 12800*480
  int row = i / 480;
  int c = i - row * 480;
  int j = c / 48;
  int h0 = (c - j * 48) * 8;
  int b = row / 50, t = row - b * 50;
  int s = t - 9 + j;
  f16x8 o;
  if (s >= 0) {
    float wv = ld[row * 10 + j];
    const float* hp = h_all + ((long)s * 256 + b) * 384 + h0;
#pragma unroll
    for (int k = 0; k < 8; k++) o[k] = (f16)(wv * hp[k]);
  } else {
#pragma unroll
    for (int k = 0; k < 8; k++) o[k] = (f16)0.0f;
  }
  *(f16x8*)(lh + (long)row * KH + j * 384 + h0) = o;
}

// mlh_h[(b,t)][h] = mean_j (f16)
__global__ __launch_bounds__(256) void k_mlh(const float* __restrict__ ld,
                                             const float* __restrict__ h_all,
                                             f16* __restrict__ mlh) {
  int i = blockIdx.x * 256 + threadIdx.x;   // 12800*384
  int row = i / 384, h = i - row * 384;
  int b = row / 50, t = row - b * 50;
  float acc = 0.0f;
#pragma unroll
  for (int j = 0; j < 10; j++) {
    int s = t - 9 + j;
    if (s >= 0) acc += ld[row * 10 + j] * h_all[((long)s * 256 + b) * 384 + h];
  }
  mlh[i] = (f16)(acc * 0.1f);
}

// rnn_f16[b][t*384+h] = theme*conv + h
__global__ __launch_bounds__(256) void k_rnn(const float* __restrict__ theme,
                                             const float* __restrict__ conv,
                                             const float* __restrict__ h_all,
                                             f16* __restrict__ rnn) {
  int i = blockIdx.x * 256 + threadIdx.x;   // 12800*384, ordered (b,t,h)
  int row = i / 384, h = i - row * 384;
  int b = row / 50, t = row - b * 50;
  float local = theme[i] * conv[i];
  float hv = h_all[((long)t * 256 + b) * 384 + h];
  rnn[i] = (f16)(local + hv);               // (b*50+t)*384+h == b*19200 + t*384 + h
}

// out[i] = sum_z part[z][i] + out_b
__global__ __launch_bounds__(256) void k_red8(const float* __restrict__ part,
                                              const float* __restrict__ ob,
                                              float* __restrict__ out) {
  int i = blockIdx.x * 256 + threadIdx.x;   // 32768
  float s = 0.0f;
#pragma unroll
  for (int z = 0; z < 8; z++) s += part[z * 32768 + i];
  out[i] = s + ob[i & 127];
}

// ---------------- launch ----------------
extern "C" void kernel_launch(void* const* d_in, const int* in_sizes, int n_in,
                              void* d_out, int out_size, void* d_ws, size_t ws_size,
                              hipStream_t stream) {
  (void)in_sizes; (void)n_in; (void)out_size; (void)ws_size;
  const int*   node_ids  = (const int*)  d_in[0];
  const float* timep     = (const float*)d_in[3];
  const float* embed     = (const float*)d_in[6];
  const float* kernel_w  = (const float*)d_in[7];
  const float* kernel_b  = (const float*)d_in[8];
  const float* rec_w     = (const float*)d_in[9];
  const float* rec_b     = (const float*)d_in[10];
  const float* scale_w   = (const float*)d_in[11];
  const float* scale_b   = (const float*)d_in[12];
  const float* rescale_w = (const float*)d_in[13];
  const float* rescale_b = (const float*)d_in[14];
  const float* conv_w    = (const float*)d_in[15];
  const float* conv_b    = (const float*)d_in[16];
  const float* out_w     = (const float*)d_in[17];
  const float* out_b     = (const float*)d_in[18];

  char* ws = (char*)d_ws;
  f16*   xf      = (f16*)  (ws + OFF_X);
  f16*   lh      = (f16*)  (ws + OFF_LH);
  float* opart   = (float*)(ws + OFF_OPART);
  f16*   Wk      = (f16*)  (ws + OFF_WK);
  f16*   XKh     = (f16*)  (ws + OFF_XK);
  f16*   mlh_h   = (f16*)  (ws + OFF_MLH);
  f16*   s1h     = (f16*)  (ws + OFF_S1);
  float* theme   = (float*)(ws + OFF_TH);
  float* convbuf = (float*)(ws + OFF_CV);
  f16*   swp     = (f16*)  (ws + OFF_SWP);
  f16*   rwp2    = (f16*)  (ws + OFF_RWP2);
  float* sbp     = (float*)(ws + OFF_SBP);
  f16*   RW      = (f16*)  (ws + OFF_RW);
  float* Sv      = (float*)(ws + OFF_SV);
  float* biasc   = (float*)(ws + OFF_BIASC);
  float* h_all   = (float*)(ws + OFF_HALL);
  float* ldbuf   = (float*)(ws + OFF_LD);
  f16*   Wc2     = (f16*)  (ws + OFF_WC2);
  f16*   rnn     = (f16*)  (ws + OFF_RNN);
  f16*   outw    = (f16*)  (ws + OFF_OUTW);

  float* outp  = (float*)d_out;          // (256,128)
  float* dists = outp + 256 * 128;       // (50,256)

  // phase 0: prep
  k_gather    <<<25600, 256, 0, stream>>>(node_ids, embed, xf);
  k_prep_wk   <<<26624, 256, 0, stream>>>(kernel_w, kernel_b, rec_b, Wk, biasc);
  k_prep_rw   <<<2496,  256, 0, stream>>>(rec_w, kernel_w, RW, Sv);
  k_prep_scale<<<192,   256, 0, stream>>>(scale_w, scale_b, rescale_w, swp, sbp, rwp2);
  k_prep_wc   <<<5760,  256, 0, stream>>>(conv_w, Wc2);
  // phase 1: XKh = f16( x @ kernel_w^T + (kernel_b + rec_b) )
  k_gemm_bt<<<dim3(100, 13), 256, 0, stream>>>(xf, Wk, XKh, biasc, GP, 4096, 4096, 1);
  // phase 2: sequential recurrence (weights-stationary in registers)
  k_recur<<<16, 1024, 0, stream>>>(XKh, RW, Sv, timep, h_all, dists);
  // phase 3: deferred outputs (fully parallel)
  k_ld  <<<50,    256, 0, stream>>>(dists, ldbuf);
  k_lh  <<<24000, 256, 0, stream>>>(ldbuf, h_all, lh);
  k_mlh <<<19200, 256, 0, stream>>>(ldbuf, h_all, mlh_h);
  k_gemm_bt<<<dim3(100, 1), 256, 0, stream>>>(mlh_h, swp, s1h, sbp, 128, 384, 384, 2);
  k_gemm_bt<<<dim3(100, 3), 256, 0, stream>>>(s1h, rwp2, theme, rescale_b, 384, 128, 128, 3);
  k_gemm_bt<<<dim3(100, 3), 256, 0, stream>>>(lh, Wc2, convbuf, conv_b, 384, KH, KH, 0);
  k_rnn <<<19200, 256, 0, stream>>>(theme, convbuf, h_all, rnn);
  k_cvt <<<9600,  256, 0, stream>>>(out_w, outw, 128L * KO);
  // phase 4: out = rnn @ out_w^T + out_b   (K split 8 ways, then reduce)
  k_gemm_bt<<<dim3(2, 1, 8), 256, 0, stream>>>(rnn, outw, opart, nullptr, 128, KO, KO / 8, 0);
  k_red8<<<128, 256, 0, stream>>>(opart, out_b, outp);
}

// Round 5
// 2413.792 us; speedup vs baseline: 1.1160x; 1.1160x over previous
//
#include <hip/hip_runtime.h>
#include <math.h>

// ---------------- types ----------------
typedef _Float16 f16;
typedef _Float16 f16x8 __attribute__((ext_vector_type(8)));
typedef float f32x4 __attribute__((ext_vector_type(4)));

#define DEV static __device__ __forceinline__

DEV float sigm(float x)  { return 1.0f / (1.0f + __expf(-x)); }
DEV float tanhfast(float x) { return 2.0f / (1.0f + __expf(-2.0f * x)) - 1.0f; }

// async global->LDS, 16B per lane (dest must be wave-uniform base + lane*16)
DEV void gld16(const void* g, void* l) {
  __builtin_amdgcn_global_load_lds((const __attribute__((address_space(1))) void*)g,
                                   (__attribute__((address_space(3))) void*)l, 16, 0, 0);
}

// ---------------- problem constants ----------------
// B=256 V=50 N=32 D=128 H=384 L=12 CS=10 ND=4096 G=1560 OUT=128
#define GP 1664   // padded G (13*128) — XK gemm N and XKh row stride
#define XOS 1576  // xo LDS row stride f16
#define HXS 416   // hext LDS row stride f16
#define KH 3840   // H*CS (conv gemm K)
#define KO 19200  // V*H  (out gemm K)

// k_recur dynamic LDS layout (bytes):
//   [0,98304)        8 waves x 2 x 6144 RW staging buffers
//   [98304,148736)   xo   16 x 1576 f16
//   [148736,162048)  hext 16 x 416  f16
//   [162048,162112)  tvs  16 f32
#define RECUR_LDS 162112

// ---------------- workspace layout (bytes) ----------------
static constexpr size_t OFF_X     = 0;                       // xf 104857600; lh aliases; opart aliases
static constexpr size_t OFF_LH    = 0;
static constexpr size_t OFF_OPART = 0;
static constexpr size_t OFF_WK    = 104857600;               // 13631488
static constexpr size_t OFF_XK    = OFF_WK + 13631488;       // XKh f16 12800*1664*2 = 42598400
// aliases of the XK region (XKh dead after k_recur; swp/rwp2/sbp live beyond 42.6MB mark):
static constexpr size_t OFF_MLH   = OFF_XK;                  // mlh_h f16 9830400
static constexpr size_t OFF_S1    = OFF_XK + 9830400;        // s1h f16 3276800
static constexpr size_t OFF_TH    = OFF_XK + 13107200;       // theme f32 19660800
static constexpr size_t OFF_CV    = OFF_XK + 32768000;       // conv f32 19660800 (ends +52428800)
static constexpr size_t OFF_SWP   = OFF_XK + 52428800;       // swp f16 98304 (> XKh end)
static constexpr size_t OFF_RWP2  = OFF_XK + 52527104;       // rwp2 f16 98304
static constexpr size_t OFF_SBP   = OFF_XK + 52625408;       // sbp f32 512
static constexpr size_t OFF_RW    = OFF_XK + 85196800;       // RWpack f16 98*12288 = 1204224
static constexpr size_t OFF_SV    = OFF_RW + 1277952;        // Sv f32 6656
static constexpr size_t OFF_BIASC = OFF_RW + 1384448;        // 8192
static constexpr size_t OFF_HALL  = OFF_BIASC + 8192;        // h_all f32 19660800
static constexpr size_t OFF_LD    = OFF_HALL + 19660800;     // 512000
static constexpr size_t OFF_WC2   = OFF_LD + 512000;         // 2949120
static constexpr size_t OFF_RNN   = OFF_WC2 + 2949120;       // 9830400
static constexpr size_t OFF_OUTW  = OFF_RNN + 9830400;       // 4915200

// ---------------- kernels ----------------

// embedding gather -> x_f16 (12800 x 4096), 8 halfs / thread
__global__ __launch_bounds__(256) void k_gather(const int* __restrict__ ids,
                                                const float* __restrict__ embed,
                                                f16* __restrict__ xf) {
  int i = blockIdx.x * 256 + threadIdx.x;     // 12800*512 total
  int row = i >> 9;
  int c8  = i & 511;
  int n = c8 >> 4;
  int d = (c8 & 15) << 3;
  int id = ids[row * 32 + n];
  const float* e = embed + (long)id * 128 + d;
  float4 a = *(const float4*)e;
  float4 b = *(const float4*)(e + 4);
  f16x8 o;
  o[0]=(f16)a.x; o[1]=(f16)a.y; o[2]=(f16)a.z; o[3]=(f16)a.w;
  o[4]=(f16)b.x; o[5]=(f16)b.y; o[6]=(f16)b.z; o[7]=(f16)b.w;
  *(f16x8*)(xf + ((long)row << 12) + (c8 << 3)) = o;
}

// kernel_w (1560 x 4097) -> Wk_f16 (1664 x 4096, zero-padded rows); biasc = kb+rb (padded 1664)
__global__ __launch_bounds__(256) void k_prep_wk(const float* __restrict__ kw,
                                                 const float* __restrict__ kb,
                                                 const float* __restrict__ rb,
                                                 f16* __restrict__ Wk,
                                                 float* __restrict__ biasc) {
  long i = (long)blockIdx.x * 256 + threadIdx.x;
  if (i < 1664L * 4096) {
    int nn = (int)(i >> 12);
    int k  = (int)(i & 4095);
    float v = (nn < 1560) ? kw[(long)nn * 4097 + k] : 0.0f;
    Wk[i] = (f16)v;
  }
  if (i < 1664) biasc[i] = (i < 1560) ? (kb[i] + rb[i]) : 0.0f;
}

// rec_w (1560x385) -> RWpack: per-lane MFMA B-fragment order.
// RWpack[nt][f][l][e] (f16), offset halfs = ((nt*12+f)*64+l)*8:
//   value = rec_w[row = nt*16+(l&15)][k = f*32+(l>>4)*8+e]  (rows>=1560 -> 0)
// Sv[n] = rec_w[n][384] + kernel_w[n][4096]
__global__ __launch_bounds__(512) void k_prep_rwpack(const float* __restrict__ rw,
                                                     const float* __restrict__ kw,
                                                     f16* __restrict__ RWp,
                                                     float* __restrict__ Sv) {
  int i = blockIdx.x * 512 + threadIdx.x;      // 98*12*64 = 75264 chunks of 8 halfs
  if (i < 75264) {
    int nt = i / 768;
    int rem = i - nt * 768;
    int f = rem >> 6;
    int l = rem & 63;
    int row = nt * 16 + (l & 15);
    int k = f * 32 + ((l >> 4) << 3);
    f16x8 o;
    if (row < 1560) {
      const float* s = rw + (long)row * 385 + k;
#pragma unroll
      for (int e = 0; e < 8; ++e) o[e] = (f16)s[e];
    } else {
#pragma unroll
      for (int e = 0; e < 8; ++e) o[e] = (f16)0.0f;
    }
    *(f16x8*)(RWp + (long)i * 8) = o;
  }
  if (i < 1664)
    Sv[i] = (i < 1560) ? (rw[(long)i * 385 + 384] + kw[(long)i * 4097 + 4096]) : 0.0f;
}

// conv_w (384,384,10) -> Wc2_f16[o][j*384+h]
__global__ __launch_bounds__(256) void k_prep_wc(const float* __restrict__ cw,
                                                 f16* __restrict__ Wc2) {
  int i = blockIdx.x * 256 + threadIdx.x;     // 384*3840
  if (i >= 384 * 3840) return;
  int o = i / 3840;
  int c = i - o * 3840;
  int j = c / 384;
  int h = c - j * 384;
  Wc2[i] = (f16)cw[((long)o * 384 + h) * 10 + j];
}

// scale_w (64,384)->swp(128,384,f16,zero-pad rows); scale_b->sbp(128); rescale_w(384,64)->rwp2(384,128,zero-pad cols)
__global__ __launch_bounds__(256) void k_prep_scale(const float* __restrict__ sw,
                                                    const float* __restrict__ sb,
                                                    const float* __restrict__ rw2,
                                                    f16* __restrict__ swp,
                                                    float* __restrict__ sbp,
                                                    f16* __restrict__ rwp2) {
  int i = blockIdx.x * 256 + threadIdx.x;   // 49152
  if (i < 128 * 384) {
    int o = i / 384, k = i - o * 384;
    swp[i] = (f16)((o < 64) ? sw[o * 384 + k] : 0.0f);
    int o2 = i >> 7, k2 = i & 127;
    rwp2[i] = (f16)((k2 < 64) ? rw2[o2 * 64 + k2] : 0.0f);
  }
  if (i < 128) sbp[i] = (i < 64) ? sb[i] : 0.0f;
}

// generic fp32 -> f16 convert
__global__ __launch_bounds__(256) void k_cvt(const float* __restrict__ src,
                                             f16* __restrict__ dst, long n) {
  long i = (long)blockIdx.x * 256 + threadIdx.x;
  if (i < n) dst[i] = (f16)src[i];
}

// C = A(M x K) * W(N x K)^T (+bias[col]); m97-style global_load_lds staging.
// grid.z splits K (writes partials at z*M*N). act: 0=f32, 1=f16, 2=relu->f16, 3=sigmoid->f32.
__global__ __launch_bounds__(256) void k_gemm_bt(const f16* __restrict__ A,
                                                 const f16* __restrict__ W,
                                                 void* __restrict__ Cv,
                                                 const float* __restrict__ bias,
                                                 int N, int K, int kLen, int act) {
  __shared__ __align__(16) f16 As[128 * 32];   // unpadded: global_load_lds needs lane-contiguous dest
  __shared__ __align__(16) f16 Bs[128 * 32];
  const int tid = threadIdx.x;
  const long rowA0 = (long)blockIdx.x * 128;
  const long rowB0 = (long)blockIdx.y * 128;
  const long ks = (long)blockIdx.z * kLen;
  const long zoff = (long)blockIdx.z * ((long)gridDim.x * 128 * N);
  const int w = tid >> 6, lane = tid & 63;
  const int q = lane >> 4, r16 = lane & 15;
  const int wr = w >> 1, wc = w & 1;
  f32x4 acc[4][4] = {};
  const int srow = tid >> 2;
  const int scol = (tid & 3) * 8;
  const f16* gA0 = A + (rowA0 + srow) * (long)K + ks + scol;
  const f16* gA1 = gA0 + 64L * K;
  const f16* gB0 = W + (rowB0 + srow) * (long)K + ks + scol;
  const f16* gB1 = gB0 + 64L * K;
  f16* lA = As + tid * 8;
  f16* lB = Bs + tid * 8;
  for (int k0 = 0; k0 < kLen; k0 += 32) {
    __syncthreads();
    gld16(gA0 + k0, lA);
    gld16(gA1 + k0, lA + 2048);
    gld16(gB0 + k0, lB);
    gld16(gB1 + k0, lB + 2048);
    __syncthreads();
    f16x8 af[4], bfr[4];
#pragma unroll
    for (int i = 0; i < 4; i++) {
      af[i]  = *(const f16x8*)&As[(wr * 64 + i * 16 + r16) * 32 + q * 8];
      bfr[i] = *(const f16x8*)&Bs[(wc * 64 + i * 16 + r16) * 32 + q * 8];
    }
#pragma unroll
    for (int i = 0; i < 4; i++)
#pragma unroll
      for (int j = 0; j < 4; j++)
        acc[i][j] = __builtin_amdgcn_mfma_f32_16x16x32_f16(af[i], bfr[j], acc[i][j], 0, 0, 0);
  }
#pragma unroll
  for (int i = 0; i < 4; i++)
#pragma unroll
    for (int j = 0; j < 4; j++) {
      long row = rowA0 + wr * 64 + i * 16 + q * 4;
      long col = rowB0 + wc * 64 + j * 16 + r16;
      float bv = bias ? bias[col] : 0.0f;
#pragma unroll
      for (int r = 0; r < 4; r++) {
        float v = acc[i][j][r] + bv;
        long off = (row + r) * (long)N + col + zoff;
        if (act == 0)      ((float*)Cv)[off] = v;
        else if (act == 1) ((f16*)Cv)[off]   = (f16)v;
        else if (act == 2) ((f16*)Cv)[off]   = (f16)fmaxf(v, 0.0f);
        else               ((float*)Cv)[off] = sigm(v);
      }
    }
}

// sequential scan v3: 16 blocks x 16 batches x 512 threads (8 waves).
// RW streamed L2->LDS via global_load_lds (zero VGPR cost), per-wave half-tile
// double buffer, barrier-drain pipelining (m97 pattern). Weights pre-packed in
// per-lane fragment order -> DMA image == conflict-free ds_read_b128 pattern.
__global__ __launch_bounds__(512)
void k_recur(const f16* __restrict__ XKh,    // (12800,1664) f16, bias folded
             const f16* __restrict__ RWp,    // packed (98,12,64,8) f16
             const float* __restrict__ Sv,   // (1664)
             const float* __restrict__ timep,
             float* __restrict__ h_all,      // (50,256,384)
             float* __restrict__ dists) {    // (50,256)
  extern __shared__ char smem[];
  const int tid = threadIdx.x;
  const int b0 = blockIdx.x * 16;
  const int w = tid >> 6, lane = tid & 63;
  const int q = lane >> 4, r16 = lane & 15;
  char* wbuf  = smem + w * 12288;               // 2 x 6144 per wave
  f16*  xo    = (f16*)(smem + 98304);           // 16 x XOS
  f16*  hext  = (f16*)(smem + 148736);          // 16 x HXS
  float* tvs  = (float*)(smem + 162048);        // 16
  // tile assignment: waves 0,1 -> 13 tiles; waves 2..7 -> 12 (98 total)
  const int cntw   = (w < 2) ? 13 : 12;
  const int tstart = (w < 2) ? w * 13 : 26 + (w - 2) * 12;
  const int rmax   = 2 * cntw;
  for (int i = tid; i < 16 * HXS; i += 512) hext[i] = (f16)0;
  if (tid < 16) tvs[tid] = timep[(b0 + tid) * 50];
  const int gm = tid >> 5, gch = tid & 31;      // gate mapping: (batch, channel)
  float creg[12] = {};

  for (int t = 0; t < 50; ++t) {
    __syncthreads();   // hext/tvs ready; xo of step t-1 fully consumed
    f16x8 af[12];
    const f16* hrow = hext + r16 * HXS + q * 8;
#pragma unroll
    for (int f = 0; f < 12; ++f) af[f] = *(const f16x8*)(hrow + f * 32);
    float tvr[4];
#pragma unroll
    for (int rr = 0; rr < 4; ++rr) tvr[rr] = tvs[q * 4 + rr];
    // pre-issue granule 0 (tile tstart, f 0..5) into buf0
    {
      const char* src = (const char*)RWp + (size_t)tstart * 12288;
#pragma unroll
      for (int j = 0; j < 6; ++j)
        gld16(src + j * 1024 + lane * 16, wbuf + j * 1024 + lane * 16);
    }
    f32x4 a0 = {0.f, 0.f, 0.f, 0.f};
    f16 xkc[4] = {};
    float Sc = 0.f;
    const f16* xkrow0 = XKh + ((long)(b0 + q * 4) * 50 + t) * GP + r16;
    for (int r = 0; r < 26; ++r) {
      __syncthreads();                   // drains DMA -> buf[r&1] ready; buf[(r+1)&1] free
      const int nr = r + 1;
      if (nr < rmax) {                   // issue granule nr into buf[nr&1]
        const char* src = (const char*)RWp + (size_t)(tstart + (nr >> 1)) * 12288 + (size_t)(nr & 1) * 6144;
        char* dst = wbuf + (nr & 1) * 6144;
#pragma unroll
        for (int j = 0; j < 6; ++j)
          gld16(src + j * 1024 + lane * 16, dst + j * 1024 + lane * 16);
      }
      if (r < rmax) {
        const int g = r & 1;
        const int ti = tstart + (r >> 1);
        if (g == 0) {                    // per-tile scalars, consumed end of next round
#pragma unroll
          for (int rr = 0; rr < 4; ++rr) xkc[rr] = xkrow0[(long)rr * 50 * GP + ti * 16];
          Sc = Sv[ti * 16 + r16];
        }
        const f16* bsrc = (const f16*)(wbuf + g * 6144) + lane * 8;
#pragma unroll
        for (int fp = 0; fp < 6; ++fp) {
          f16x8 bw = *(const f16x8*)(bsrc + fp * 512);
          a0 = __builtin_amdgcn_mfma_f32_16x16x32_f16(af[g * 6 + fp], bw, a0, 0, 0, 0);
        }
        if (g == 1) {
          const int c0 = ti * 16 + r16;
#pragma unroll
          for (int rr = 0; rr < 4; ++rr)
            xo[(q * 4 + rr) * XOS + c0] = (f16)(a0[rr] + (float)xkc[rr] + tvr[rr] * Sc);
          a0[0] = 0.f; a0[1] = 0.f; a0[2] = 0.f; a0[3] = 0.f;
        }
      }
    }
    __syncthreads();   // xo ready
    // gates: thread = (batch gm, channel gch)
    {
      const f16* xom = xo + gm * XOS;
      const int b = b0 + gm;
      float fm[12], im[12];
      {
        float v1[12], v2[12], mx1 = -1e30f, mx2 = -1e30f;
#pragma unroll
        for (int l = 0; l < 12; l++) {
          v1[l] = (float)xom[l];      mx1 = fmaxf(mx1, v1[l]);
          v2[l] = (float)xom[12 + l]; mx2 = fmaxf(mx2, v2[l]);
        }
        float s1 = 0.0f, s2 = 0.0f;
#pragma unroll
        for (int l = 0; l < 12; l++) {
          v1[l] = __expf(v1[l] - mx1); s1 += v1[l];
          v2[l] = __expf(v2[l] - mx2); s2 += v2[l];
        }
        float i1 = 1.0f / s1, i2 = 1.0f / s2, c1 = 0.0f, c2 = 0.0f;
#pragma unroll
        for (int l = 0; l < 12; l++) { c1 += v1[l]; fm[l] = c1 * i1; }
#pragma unroll
        for (int l = 11; l >= 0; l--) { c2 += v2[l]; im[l] = c2 * i2; }
      }
      if (gch == 0) {
        float ds = 0.0f;
#pragma unroll
        for (int l = 0; l < 12; l++) ds += fm[l];
        dists[t * 256 + b] = 1.0f - ds * (1.0f / 12.0f);
      }
      float* hdst = h_all + ((long)t * 256 + b) * 384;
#pragma unroll
      for (int l = 0; l < 12; l++) {
        float fv = sigm((float)xom[24 + l * 32 + gch]);
        float iv = sigm((float)xom[24 + (12 + l) * 32 + gch]);
        float og = sigm((float)xom[24 + (24 + l) * 32 + gch]);
        float ci = tanhfast((float)xom[24 + (36 + l) * 32 + gch]);
        float fmv = fm[l], imv = im[l], ov = fmv * imv;
        float cn = ov * (fv * creg[l] + iv * ci) + (fmv - ov) * creg[l] + (imv - ov) * ci;
        creg[l] = cn;
        float hv = og * tanhfast(cn);
        hdst[l * 32 + gch] = hv;
        hext[gm * HXS + l * 32 + gch] = (f16)hv;
      }
      if (gch == 1 && t < 49) tvs[gm] = timep[b * 50 + t + 1];
    }
  }
}

// ld[b,t,:] = softmax_j(cumsum_j dist[t-9+j])
__global__ __launch_bounds__(256) void k_ld(const float* __restrict__ dists,
                                            float* __restrict__ ld) {
  int i = blockIdx.x * 256 + threadIdx.x;
  if (i >= 12800) return;
  int b = i / 50, t = i - b * 50;
  float v[10];
  float cum = 0.0f, mx = -1e30f;
#pragma unroll
  for (int j = 0; j < 10; j++) {
    int s = t - 9 + j;
    float d = (s >= 0) ? dists[s * 256 + b] : 0.0f;
    cum += d; v[j] = cum; mx = fmaxf(mx, cum);
  }
  float sum = 0.0f;
#pragma unroll
  for (int j = 0; j < 10; j++) { v[j] = __expf(v[j] - mx); sum += v[j]; }
  float inv = 1.0f / sum;
#pragma unroll
  for (int j = 0; j < 10; j++) ld[i * 10 + j] = v[j] * inv;
}

// lh_f16[(b,t)][j*384+h] = ld[b,t,j] * h_{t-9+j}[b,h]
__global__ __launch_bounds__(256) void k_lh(const float* __restrict__ ld,
                                            const float* __restrict__ h_all,
                                            f16* __restrict__ lh) {
  int i = blockIdx.x * 256 + threadIdx.x;   // 12800*480
  int row = i / 480;
  int c = i - row * 480;
  int j = c / 48;
  int h0 = (c - j * 48) * 8;
  int b = row / 50, t = row - b * 50;
  int s = t - 9 + j;
  f16x8 o;
  if (s >= 0) {
    float wv = ld[row * 10 + j];
    const float* hp = h_all + ((long)s * 256 + b) * 384 + h0;
#pragma unroll
    for (int k = 0; k < 8; k++) o[k] = (f16)(wv * hp[k]);
  } else {
#pragma unroll
    for (int k = 0; k < 8; k++) o[k] = (f16)0.0f;
  }
  *(f16x8*)(lh + (long)row * KH + j * 384 + h0) = o;
}

// mlh_h[(b,t)][h] = mean_j (f16)
__global__ __launch_bounds__(256) void k_mlh(const float* __restrict__ ld,
                                             const float* __restrict__ h_all,
                                             f16* __restrict__ mlh) {
  int i = blockIdx.x * 256 + threadIdx.x;   // 12800*384
  int row = i / 384, h = i - row * 384;
  int b = row / 50, t = row - b * 50;
  float acc = 0.0f;
#pragma unroll
  for (int j = 0; j < 10; j++) {
    int s = t - 9 + j;
    if (s >= 0) acc += ld[row * 10 + j] * h_all[((long)s * 256 + b) * 384 + h];
  }
  mlh[i] = (f16)(acc * 0.1f);
}

// rnn_f16[b][t*384+h] = theme*conv + h
__global__ __launch_bounds__(256) void k_rnn(const float* __restrict__ theme,
                                             const float* __restrict__ conv,
                                             const float* __restrict__ h_all,
                                             f16* __restrict__ rnn) {
  int i = blockIdx.x * 256 + threadIdx.x;   // 12800*384, ordered (b,t,h)
  int row = i / 384, h = i - row * 384;
  int b = row / 50, t = row - b * 50;
  float local = theme[i] * conv[i];
  float hv = h_all[((long)t * 256 + b) * 384 + h];
  rnn[i] = (f16)(local + hv);               // (b*50+t)*384+h == b*19200 + t*384 + h
}

// out[i] = sum_z part[z][i] + out_b
__global__ __launch_bounds__(256) void k_red8(const float* __restrict__ part,
                                              const float* __restrict__ ob,
                                              float* __restrict__ out) {
  int i = blockIdx.x * 256 + threadIdx.x;   // 32768
  float s = 0.0f;
#pragma unroll
  for (int z = 0; z < 8; z++) s += part[z * 32768 + i];
  out[i] = s + ob[i & 127];
}

// ---------------- launch ----------------
extern "C" void kernel_launch(void* const* d_in, const int* in_sizes, int n_in,
                              void* d_out, int out_size, void* d_ws, size_t ws_size,
                              hipStream_t stream) {
  (void)in_sizes; (void)n_in; (void)out_size; (void)ws_size;
  const int*   node_ids  = (const int*)  d_in[0];
  const float* timep     = (const float*)d_in[3];
  const float* embed     = (const float*)d_in[6];
  const float* kernel_w  = (const float*)d_in[7];
  const float* kernel_b  = (const float*)d_in[8];
  const float* rec_w     = (const float*)d_in[9];
  const float* rec_b     = (const float*)d_in[10];
  const float* scale_w   = (const float*)d_in[11];
  const float* scale_b   = (const float*)d_in[12];
  const float* rescale_w = (const float*)d_in[13];
  const float* rescale_b = (const float*)d_in[14];
  const float* conv_w    = (const float*)d_in[15];
  const float* conv_b    = (const float*)d_in[16];
  const float* out_w     = (const float*)d_in[17];
  const float* out_b     = (const float*)d_in[18];

  char* ws = (char*)d_ws;
  f16*   xf      = (f16*)  (ws + OFF_X);
  f16*   lh      = (f16*)  (ws + OFF_LH);
  float* opart   = (float*)(ws + OFF_OPART);
  f16*   Wk      = (f16*)  (ws + OFF_WK);
  f16*   XKh     = (f16*)  (ws + OFF_XK);
  f16*   mlh_h   = (f16*)  (ws + OFF_MLH);
  f16*   s1h     = (f16*)  (ws + OFF_S1);
  float* theme   = (float*)(ws + OFF_TH);
  float* convbuf = (float*)(ws + OFF_CV);
  f16*   swp     = (f16*)  (ws + OFF_SWP);
  f16*   rwp2    = (f16*)  (ws + OFF_RWP2);
  float* sbp     = (float*)(ws + OFF_SBP);
  f16*   RWp     = (f16*)  (ws + OFF_RW);
  float* Sv      = (float*)(ws + OFF_SV);
  float* biasc   = (float*)(ws + OFF_BIASC);
  float* h_all   = (float*)(ws + OFF_HALL);
  float* ldbuf   = (float*)(ws + OFF_LD);
  f16*   Wc2     = (f16*)  (ws + OFF_WC2);
  f16*   rnn     = (f16*)  (ws + OFF_RNN);
  f16*   outw    = (f16*)  (ws + OFF_OUTW);

  float* outp  = (float*)d_out;          // (256,128)
  float* dists = outp + 256 * 128;       // (50,256)

  // phase 0: prep
  k_gather     <<<25600, 256, 0, stream>>>(node_ids, embed, xf);
  k_prep_wk    <<<26624, 256, 0, stream>>>(kernel_w, kernel_b, rec_b, Wk, biasc);
  k_prep_rwpack<<<147,   512, 0, stream>>>(rec_w, kernel_w, RWp, Sv);
  k_prep_scale <<<192,   256, 0, stream>>>(scale_w, scale_b, rescale_w, swp, sbp, rwp2);
  k_prep_wc    <<<5760,  256, 0, stream>>>(conv_w, Wc2);
  // phase 1: XKh = f16( x @ kernel_w^T + (kernel_b + rec_b) )
  k_gemm_bt<<<dim3(100, 13), 256, 0, stream>>>(xf, Wk, XKh, biasc, GP, 4096, 4096, 1);
  // phase 2: sequential recurrence (RW streamed L2->LDS via async DMA)
  static int lds_opt_in = 0;
  (void)lds_opt_in;
  hipFuncSetAttribute((const void*)k_recur, hipFuncAttributeMaxDynamicSharedMemorySize, RECUR_LDS);
  k_recur<<<16, 512, RECUR_LDS, stream>>>(XKh, RWp, Sv, timep, h_all, dists);
  // phase 3: deferred outputs (fully parallel)
  k_ld  <<<50,    256, 0, stream>>>(dists, ldbuf);
  k_lh  <<<24000, 256, 0, stream>>>(ldbuf, h_all, lh);
  k_mlh <<<19200, 256, 0, stream>>>(ldbuf, h_all, mlh_h);
  k_gemm_bt<<<dim3(100, 1), 256, 0, stream>>>(mlh_h, swp, s1h, sbp, 128, 384, 384, 2);
  k_gemm_bt<<<dim3(100, 3), 256, 0, stream>>>(s1h, rwp2, theme, rescale_b, 384, 128, 128, 3);
  k_gemm_bt<<<dim3(100, 3), 256, 0, stream>>>(lh, Wc2, convbuf, conv_b, 384, KH, KH, 0);
  k_rnn <<<19200, 256, 0, stream>>>(theme, convbuf, h_all, rnn);
  k_cvt <<<9600,  256, 0, stream>>>(out_w, outw, 128L * KO);
  // phase 4: out = rnn @ out_w^T + out_b   (K split 8 ways, then reduce)
  k_gemm_bt<<<dim3(2, 1, 8), 256, 0, stream>>>(rnn, outw, opart, nullptr, 128, KO, KO / 8, 0);
  k_red8<<<128, 256, 0, stream>>>(opart, out_b, outp);
}

// Round 6
// 1946.490 us; speedup vs baseline: 1.3840x; 1.2401x over previous
//
#include <hip/hip_runtime.h>
#include <hip/hip_cooperative_groups.h>
#include <math.h>

namespace cg = cooperative_groups;

// ---------------- types ----------------
typedef _Float16 f16;
typedef _Float16 f16x8 __attribute__((ext_vector_type(8)));
typedef float f32x4 __attribute__((ext_vector_type(4)));

#define DEV static __device__ __forceinline__

DEV float sigm(float x)  { return 1.0f / (1.0f + __expf(-x)); }
DEV float tanhfast(float x) { return 2.0f / (1.0f + __expf(-2.0f * x)) - 1.0f; }

// async global->LDS, 16B per lane (dest must be wave-uniform base + lane*16)
DEV void gld16(const void* g, void* l) {
  __builtin_amdgcn_global_load_lds((const __attribute__((address_space(1))) void*)g,
                                   (__attribute__((address_space(3))) void*)l, 16, 0, 0);
}

// ---------------- problem constants ----------------
// B=256 V=50 N=32 D=128 H=384 L=12 CS=10 ND=4096 G=1560 OUT=128
#define GP 1664   // padded G (13*128) — XK gemm N and XKh row stride
#define XOG 1568  // xo global row stride (f16); 98 tiles cover cols 0..1567
#define KH 3840   // H*CS (conv gemm K)
#define KO 19200  // V*H  (out gemm K)

// ---------------- workspace layout (bytes) ----------------
static constexpr size_t OFF_X     = 0;                       // xf 104857600; lh/opart alias later
static constexpr size_t OFF_LH    = 0;
static constexpr size_t OFF_OPART = 0;
// k_recur-only aliases inside the (dead during recur) xf region:
static constexpr size_t OFF_XOG   = 0;                       // xo_g f16 256*1568*2 = 802816
static constexpr size_t OFF_HEXT  = 1048576;                 // hext_g f16 256*384*2 = 196608
static constexpr size_t OFF_WK    = 104857600;               // 13631488
static constexpr size_t OFF_XK    = OFF_WK + 13631488;       // XKh f16 12800*1664*2 = 42598400
// aliases of the XK region (XKh dead after k_recur):
static constexpr size_t OFF_MLH   = OFF_XK;                  // mlh_h f16 9830400
static constexpr size_t OFF_S1    = OFF_XK + 9830400;        // s1h f16 3276800
static constexpr size_t OFF_TH    = OFF_XK + 13107200;       // theme f32 19660800
static constexpr size_t OFF_CV    = OFF_XK + 32768000;       // conv f32 19660800 (ends +52428800)
static constexpr size_t OFF_SWP   = OFF_XK + 52428800;       // swp f16 98304 (> XKh end)
static constexpr size_t OFF_RWP2  = OFF_XK + 52527104;       // rwp2 f16 98304
static constexpr size_t OFF_SBP   = OFF_XK + 52625408;       // sbp f32 512
static constexpr size_t OFF_RW    = OFF_XK + 85196800;       // RWpack f16 98*6144 halfs = 1204224 B
static constexpr size_t OFF_SV    = OFF_RW + 1277952;        // Sv f32 1664*4 = 6656
static constexpr size_t OFF_BIASC = OFF_RW + 1384448;        // 8192
static constexpr size_t OFF_HALL  = OFF_BIASC + 8192;        // h_all f32 19660800
static constexpr size_t OFF_LD    = OFF_HALL + 19660800;     // 512000
static constexpr size_t OFF_WC2   = OFF_LD + 512000;         // 2949120
static constexpr size_t OFF_RNN   = OFF_WC2 + 2949120;       // 9830400
static constexpr size_t OFF_OUTW  = OFF_RNN + 9830400;       // 4915200

// ---------------- kernels ----------------

// embedding gather -> x_f16 (12800 x 4096), 8 halfs / thread
__global__ __launch_bounds__(256) void k_gather(const int* __restrict__ ids,
                                                const float* __restrict__ embed,
                                                f16* __restrict__ xf) {
  int i = blockIdx.x * 256 + threadIdx.x;     // 12800*512 total
  int row = i >> 9;
  int c8  = i & 511;
  int n = c8 >> 4;
  int d = (c8 & 15) << 3;
  int id = ids[row * 32 + n];
  const float* e = embed + (long)id * 128 + d;
  float4 a = *(const float4*)e;
  float4 b = *(const float4*)(e + 4);
  f16x8 o;
  o[0]=(f16)a.x; o[1]=(f16)a.y; o[2]=(f16)a.z; o[3]=(f16)a.w;
  o[4]=(f16)b.x; o[5]=(f16)b.y; o[6]=(f16)b.z; o[7]=(f16)b.w;
  *(f16x8*)(xf + ((long)row << 12) + (c8 << 3)) = o;
}

// kernel_w (1560 x 4097) -> Wk_f16 (1664 x 4096, zero-padded rows); biasc = kb+rb (padded 1664)
__global__ __launch_bounds__(256) void k_prep_wk(const float* __restrict__ kw,
                                                 const float* __restrict__ kb,
                                                 const float* __restrict__ rb,
                                                 f16* __restrict__ Wk,
                                                 float* __restrict__ biasc) {
  long i = (long)blockIdx.x * 256 + threadIdx.x;
  if (i < 1664L * 4096) {
    int nn = (int)(i >> 12);
    int k  = (int)(i & 4095);
    float v = (nn < 1560) ? kw[(long)nn * 4097 + k] : 0.0f;
    Wk[i] = (f16)v;
  }
  if (i < 1664) biasc[i] = (i < 1560) ? (kb[i] + rb[i]) : 0.0f;
}

// rec_w (1560x385) -> RWpack: per-lane MFMA B-fragment order.
// RWpack[nt][f][l][e] (f16), offset halfs = ((nt*12+f)*64+l)*8:
//   value = rec_w[row = nt*16+(l&15)][k = f*32+(l>>4)*8+e]  (rows>=1560 -> 0)
// Sv[n] = rec_w[n][384] + kernel_w[n][4096]
__global__ __launch_bounds__(512) void k_prep_rwpack(const float* __restrict__ rw,
                                                     const float* __restrict__ kw,
                                                     f16* __restrict__ RWp,
                                                     float* __restrict__ Sv) {
  int i = blockIdx.x * 512 + threadIdx.x;      // 98*12*64 = 75264 chunks of 8 halfs
  if (i < 75264) {
    int nt = i / 768;
    int rem = i - nt * 768;
    int f = rem >> 6;
    int l = rem & 63;
    int row = nt * 16 + (l & 15);
    int k = f * 32 + ((l >> 4) << 3);
    f16x8 o;
    if (row < 1560) {
      const float* s = rw + (long)row * 385 + k;
#pragma unroll
      for (int e = 0; e < 8; ++e) o[e] = (f16)s[e];
    } else {
#pragma unroll
      for (int e = 0; e < 8; ++e) o[e] = (f16)0.0f;
    }
    *(f16x8*)(RWp + (long)i * 8) = o;
  }
  if (i < 1664)
    Sv[i] = (i < 1560) ? (rw[(long)i * 385 + 384] + kw[(long)i * 4097 + 4096]) : 0.0f;
}

// conv_w (384,384,10) -> Wc2_f16[o][j*384+h]
__global__ __launch_bounds__(256) void k_prep_wc(const float* __restrict__ cw,
                                                 f16* __restrict__ Wc2) {
  int i = blockIdx.x * 256 + threadIdx.x;     // 384*3840
  if (i >= 384 * 3840) return;
  int o = i / 3840;
  int c = i - o * 3840;
  int j = c / 384;
  int h = c - j * 384;
  Wc2[i] = (f16)cw[((long)o * 384 + h) * 10 + j];
}

// scale_w (64,384)->swp(128,384,f16,zero-pad rows); scale_b->sbp(128); rescale_w(384,64)->rwp2(384,128,zero-pad cols)
__global__ __launch_bounds__(256) void k_prep_scale(const float* __restrict__ sw,
                                                    const float* __restrict__ sb,
                                                    const float* __restrict__ rw2,
                                                    f16* __restrict__ swp,
                                                    float* __restrict__ sbp,
                                                    f16* __restrict__ rwp2) {
  int i = blockIdx.x * 256 + threadIdx.x;   // 49152
  if (i < 128 * 384) {
    int o = i / 384, k = i - o * 384;
    swp[i] = (f16)((o < 64) ? sw[o * 384 + k] : 0.0f);
    int o2 = i >> 7, k2 = i & 127;
    rwp2[i] = (f16)((k2 < 64) ? rw2[o2 * 64 + k2] : 0.0f);
  }
  if (i < 128) sbp[i] = (i < 64) ? sb[i] : 0.0f;
}

// generic fp32 -> f16 convert
__global__ __launch_bounds__(256) void k_cvt(const float* __restrict__ src,
                                             f16* __restrict__ dst, long n) {
  long i = (long)blockIdx.x * 256 + threadIdx.x;
  if (i < n) dst[i] = (f16)src[i];
}

// C = A(M x K) * W(N x K)^T (+bias[col]); m97-style global_load_lds staging.
// grid.z splits K (writes partials at z*M*N). act: 0=f32, 1=f16, 2=relu->f16, 3=sigmoid->f32.
__global__ __launch_bounds__(256) void k_gemm_bt(const f16* __restrict__ A,
                                                 const f16* __restrict__ W,
                                                 void* __restrict__ Cv,
                                                 const float* __restrict__ bias,
                                                 int N, int K, int kLen, int act) {
  __shared__ __align__(16) f16 As[128 * 32];   // unpadded: global_load_lds needs lane-contiguous dest
  __shared__ __align__(16) f16 Bs[128 * 32];
  const int tid = threadIdx.x;
  const long rowA0 = (long)blockIdx.x * 128;
  const long rowB0 = (long)blockIdx.y * 128;
  const long ks = (long)blockIdx.z * kLen;
  const long zoff = (long)blockIdx.z * ((long)gridDim.x * 128 * N);
  const int w = tid >> 6, lane = tid & 63;
  const int q = lane >> 4, r16 = lane & 15;
  const int wr = w >> 1, wc = w & 1;
  f32x4 acc[4][4] = {};
  const int srow = tid >> 2;
  const int scol = (tid & 3) * 8;
  const f16* gA0 = A + (rowA0 + srow) * (long)K + ks + scol;
  const f16* gA1 = gA0 + 64L * K;
  const f16* gB0 = W + (rowB0 + srow) * (long)K + ks + scol;
  const f16* gB1 = gB0 + 64L * K;
  f16* lA = As + tid * 8;
  f16* lB = Bs + tid * 8;
  for (int k0 = 0; k0 < kLen; k0 += 32) {
    __syncthreads();
    gld16(gA0 + k0, lA);
    gld16(gA1 + k0, lA + 2048);
    gld16(gB0 + k0, lB);
    gld16(gB1 + k0, lB + 2048);
    __syncthreads();
    f16x8 af[4], bfr[4];
#pragma unroll
    for (int i = 0; i < 4; i++) {
      af[i]  = *(const f16x8*)&As[(wr * 64 + i * 16 + r16) * 32 + q * 8];
      bfr[i] = *(const f16x8*)&Bs[(wc * 64 + i * 16 + r16) * 32 + q * 8];
    }
#pragma unroll
    for (int i = 0; i < 4; i++)
#pragma unroll
      for (int j = 0; j < 4; j++)
        acc[i][j] = __builtin_amdgcn_mfma_f32_16x16x32_f16(af[i], bfr[j], acc[i][j], 0, 0, 0);
  }
#pragma unroll
  for (int i = 0; i < 4; i++)
#pragma unroll
    for (int j = 0; j < 4; j++) {
      long row = rowA0 + wr * 64 + i * 16 + q * 4;
      long col = rowB0 + wc * 64 + j * 16 + r16;
      float bv = bias ? bias[col] : 0.0f;
#pragma unroll
      for (int r = 0; r < 4; r++) {
        float v = acc[i][j][r] + bv;
        long off = (row + r) * (long)N + col + zoff;
        if (act == 0)      ((float*)Cv)[off] = v;
        else if (act == 1) ((f16*)Cv)[off]   = (f16)v;
        else if (act == 2) ((f16*)Cv)[off]   = (f16)fmaxf(v, 0.0f);
        else               ((float*)Cv)[off] = sigm(v);
      }
    }
}

// cooperative weights-stationary recurrence: 32 blocks x 512 threads.
// Block owns 3-4 N-tiles; their RW fragments live in LDS for the whole kernel.
// Per step: all blocks GEMM their N-slice over all 256 batches (A = h_ext from
// global), epilogue folds XKh + tv*Sv; grid.sync; blocks 0..15 compute gates
// for 16 batches each; grid.sync.
__global__ __launch_bounds__(512)
void k_recur_coop(const f16* __restrict__ XKh,    // (12800,1664) f16, bias folded
                  const f16* __restrict__ RWp,    // packed (98,12,64,8) f16
                  const float* __restrict__ Sv,   // (1664)
                  const float* __restrict__ timep,// (256,50)
                  f16* __restrict__ xo_g,         // (256, XOG)
                  f16* __restrict__ hext_g,       // (256, 384)
                  float* __restrict__ h_all,      // (50,256,384)
                  float* __restrict__ dists) {    // (50,256)
  cg::grid_group grid = cg::this_grid();
  __shared__ __align__(16) f16 Wl[4 * 6144];      // up to 4 tiles, fragment order (49152 B)
  __shared__ float Svl[1568];                     // 6272 B
  const int tid = threadIdx.x;
  const int bid = blockIdx.x;
  const int w = tid >> 6, lane = tid & 63;
  const int q = lane >> 4, r16 = lane & 15;
  const int T = (bid < 2) ? 4 : 3;                        // 2*4 + 30*3 = 98 tiles
  const int tstart = (bid < 2) ? bid * 4 : 8 + (bid - 2) * 3;
  // stationary weights -> LDS (once)
  {
    const f16* src = RWp + (size_t)tstart * 6144;
    for (int i = tid; i < T * 768; i += 512)
      *(f16x8*)(Wl + (size_t)i * 8) = *(const f16x8*)(src + (size_t)i * 8);
  }
  for (int i = tid; i < 1568; i += 512) Svl[i] = Sv[i];
  // zero h_ext globally (grid-strided)
  {
    f16x8 z = {};
    for (int i = bid * 512 + tid; i < 12288; i += 32 * 512)
      *(f16x8*)(hext_g + (size_t)i * 8) = z;
  }
  __syncthreads();
  grid.sync();

  const int gm = tid >> 5, gch = tid & 31;        // gate mapping (blocks 0..15)
  const int gb = bid * 16 + gm;
  float creg[12] = {};

  for (int t = 0; t < 50; ++t) {
    // ---- GEMM phase: wave w -> M-tiles {2w, 2w+1}, all T local N-tiles ----
#pragma unroll
    for (int mi = 0; mi < 2; ++mi) {
      const int rowb = (w * 2 + mi) * 16;         // batch base of this M-tile
      f16x8 af[12];
      const f16* ab = hext_g + (size_t)(rowb + r16) * 384 + q * 8;
#pragma unroll
      for (int f = 0; f < 12; ++f) af[f] = *(const f16x8*)(ab + f * 32);
      float tv4[4];
#pragma unroll
      for (int r = 0; r < 4; ++r) tv4[r] = timep[(rowb + q * 4 + r) * 50 + t];
      f16 xk[4][4];
#pragma unroll
      for (int j = 0; j < 4; ++j) if (j < T) {
        const int c0 = (tstart + j) * 16;
#pragma unroll
        for (int r = 0; r < 4; ++r)
          xk[j][r] = XKh[((long)(rowb + q * 4 + r) * 50 + t) * GP + c0 + r16];
      }
#pragma unroll
      for (int j = 0; j < 4; ++j) if (j < T) {
        const int c0 = (tstart + j) * 16;
        const f16* bp = Wl + j * 6144 + lane * 8;
        f32x4 a0 = {};
#pragma unroll
        for (int f = 0; f < 12; ++f)
          a0 = __builtin_amdgcn_mfma_f32_16x16x32_f16(af[f], *(const f16x8*)(bp + f * 512), a0, 0, 0, 0);
        const float Svc = Svl[c0 + r16];
#pragma unroll
        for (int r = 0; r < 4; ++r)
          xo_g[(size_t)(rowb + q * 4 + r) * XOG + c0 + r16] = (f16)(a0[r] + (float)xk[j][r] + tv4[r] * Svc);
      }
    }
    grid.sync();   // xo ready everywhere
    // ---- gate phase (blocks 0..15; batch gb, channel gch) ----
    if (bid < 16) {
      const f16* xom = xo_g + (size_t)gb * XOG;
      float fm[12], im[12];
      {
        float v1[12], v2[12], mx1 = -1e30f, mx2 = -1e30f;
#pragma unroll
        for (int l = 0; l < 12; l++) {
          v1[l] = (float)xom[l];      mx1 = fmaxf(mx1, v1[l]);
          v2[l] = (float)xom[12 + l]; mx2 = fmaxf(mx2, v2[l]);
        }
        float s1 = 0.0f, s2 = 0.0f;
#pragma unroll
        for (int l = 0; l < 12; l++) {
          v1[l] = __expf(v1[l] - mx1); s1 += v1[l];
          v2[l] = __expf(v2[l] - mx2); s2 += v2[l];
        }
        float i1 = 1.0f / s1, i2 = 1.0f / s2, c1 = 0.0f, c2 = 0.0f;
#pragma unroll
        for (int l = 0; l < 12; l++) { c1 += v1[l]; fm[l] = c1 * i1; }
#pragma unroll
        for (int l = 11; l >= 0; l--) { c2 += v2[l]; im[l] = c2 * i2; }
      }
      if (gch == 0) {
        float ds = 0.0f;
#pragma unroll
        for (int l = 0; l < 12; l++) ds += fm[l];
        dists[t * 256 + gb] = 1.0f - ds * (1.0f / 12.0f);
      }
      float* hdst = h_all + ((long)t * 256 + gb) * 384;
#pragma unroll
      for (int l = 0; l < 12; l++) {
        float fv = sigm((float)xom[24 + l * 32 + gch]);
        float iv = sigm((float)xom[24 + (12 + l) * 32 + gch]);
        float og = sigm((float)xom[24 + (24 + l) * 32 + gch]);
        float ci = tanhfast((float)xom[24 + (36 + l) * 32 + gch]);
        float fmv = fm[l], imv = im[l], ov = fmv * imv;
        float cn = ov * (fv * creg[l] + iv * ci) + (fmv - ov) * creg[l] + (imv - ov) * ci;
        creg[l] = cn;
        float hv = og * tanhfast(cn);
        hdst[l * 32 + gch] = hv;
        hext_g[(size_t)gb * 384 + l * 32 + gch] = (f16)hv;
      }
    }
    grid.sync();   // h_ext(t) visible for GEMM(t+1)
  }
}

// ld[b,t,:] = softmax_j(cumsum_j dist[t-9+j])
__global__ __launch_bounds__(256) void k_ld(const float* __restrict__ dists,
                                            float* __restrict__ ld) {
  int i = blockIdx.x * 256 + threadIdx.x;
  if (i >= 12800) return;
  int b = i / 50, t = i - b * 50;
  float v[10];
  float cum = 0.0f, mx = -1e30f;
#pragma unroll
  for (int j = 0; j < 10; j++) {
    int s = t - 9 + j;
    float d = (s >= 0) ? dists[s * 256 + b] : 0.0f;
    cum += d; v[j] = cum; mx = fmaxf(mx, cum);
  }
  float sum = 0.0f;
#pragma unroll
  for (int j = 0; j < 10; j++) { v[j] = __expf(v[j] - mx); sum += v[j]; }
  float inv = 1.0f / sum;
#pragma unroll
  for (int j = 0; j < 10; j++) ld[i * 10 + j] = v[j] * inv;
}

// lh_f16[(b,t)][j*384+h] = ld[b,t,j] * h_{t-9+j}[b,h]
__global__ __launch_bounds__(256) void k_lh(const float* __restrict__ ld,
                                            const float* __restrict__ h_all,
                                            f16* __restrict__ lh) {
  int i = blockIdx.x * 256 + threadIdx.x;   // 12800*480
  int row = i / 480;
  int c = i - row * 480;
  int j = c / 48;
  int h0 = (c - j * 48) * 8;
  int b = row / 50, t = row - b * 50;
  int s = t - 9 + j;
  f16x8 o;
  if (s >= 0) {
    float wv = ld[row * 10 + j];
    const float* hp = h_all + ((long)s * 256 + b) * 384 + h0;
#pragma unroll
    for (int k = 0; k < 8; k++) o[k] = (f16)(wv * hp[k]);
  } else {
#pragma unroll
    for (int k = 0; k < 8; k++) o[k] = (f16)0.0f;
  }
  *(f16x8*)(lh + (long)row * KH + j * 384 + h0) = o;
}

// mlh_h[(b,t)][h] = mean_j (f16)
__global__ __launch_bounds__(256) void k_mlh(const float* __restrict__ ld,
                                             const float* __restrict__ h_all,
                                             f16* __restrict__ mlh) {
  int i = blockIdx.x * 256 + threadIdx.x;   // 12800*384
  int row = i / 384, h = i - row * 384;
  int b = row / 50, t = row - b * 50;
  float acc = 0.0f;
#pragma unroll
  for (int j = 0; j < 10; j++) {
    int s = t - 9 + j;
    if (s >= 0) acc += ld[row * 10 + j] * h_all[((long)s * 256 + b) * 384 + h];
  }
  mlh[i] = (f16)(acc * 0.1f);
}

// rnn_f16[b][t*384+h] = theme*conv + h
__global__ __launch_bounds__(256) void k_rnn(const float* __restrict__ theme,
                                             const float* __restrict__ conv,
                                             const float* __restrict__ h_all,
                                             f16* __restrict__ rnn) {
  int i = blockIdx.x * 256 + threadIdx.x;   // 12800*384, ordered (b,t,h)
  int row = i / 384, h = i - row * 384;
  int b = row / 50, t = row - b * 50;
  float local = theme[i] * conv[i];
  float hv = h_all[((long)t * 256 + b) * 384 + h];
  rnn[i] = (f16)(local + hv);               // (b*50+t)*384+h == b*19200 + t*384 + h
}

// out[i] = sum_z part[z][i] + out_b
__global__ __launch_bounds__(256) void k_red8(const float* __restrict__ part,
                                              const float* __restrict__ ob,
                                              float* __restrict__ out) {
  int i = blockIdx.x * 256 + threadIdx.x;   // 32768
  float s = 0.0f;
#pragma unroll
  for (int z = 0; z < 8; z++) s += part[z * 32768 + i];
  out[i] = s + ob[i & 127];
}

// ---------------- launch ----------------
extern "C" void kernel_launch(void* const* d_in, const int* in_sizes, int n_in,
                              void* d_out, int out_size, void* d_ws, size_t ws_size,
                              hipStream_t stream) {
  (void)in_sizes; (void)n_in; (void)out_size; (void)ws_size;
  const int*   node_ids  = (const int*)  d_in[0];
  const float* timep     = (const float*)d_in[3];
  const float* embed     = (const float*)d_in[6];
  const float* kernel_w  = (const float*)d_in[7];
  const float* kernel_b  = (const float*)d_in[8];
  const float* rec_w     = (const float*)d_in[9];
  const float* rec_b     = (const float*)d_in[10];
  const float* scale_w   = (const float*)d_in[11];
  const float* scale_b   = (const float*)d_in[12];
  const float* rescale_w = (const float*)d_in[13];
  const float* rescale_b = (const float*)d_in[14];
  const float* conv_w    = (const float*)d_in[15];
  const float* conv_b    = (const float*)d_in[16];
  const float* out_w     = (const float*)d_in[17];
  const float* out_b     = (const float*)d_in[18];

  char* ws = (char*)d_ws;
  f16*   xf      = (f16*)  (ws + OFF_X);
  f16*   lh      = (f16*)  (ws + OFF_LH);
  float* opart   = (float*)(ws + OFF_OPART);
  f16*   xo_g    = (f16*)  (ws + OFF_XOG);
  f16*   hext_g  = (f16*)  (ws + OFF_HEXT);
  f16*   Wk      = (f16*)  (ws + OFF_WK);
  f16*   XKh     = (f16*)  (ws + OFF_XK);
  f16*   mlh_h   = (f16*)  (ws + OFF_MLH);
  f16*   s1h     = (f16*)  (ws + OFF_S1);
  float* theme   = (float*)(ws + OFF_TH);
  float* convbuf = (float*)(ws + OFF_CV);
  f16*   swp     = (f16*)  (ws + OFF_SWP);
  f16*   rwp2    = (f16*)  (ws + OFF_RWP2);
  float* sbp     = (float*)(ws + OFF_SBP);
  f16*   RWp     = (f16*)  (ws + OFF_RW);
  float* Sv      = (float*)(ws + OFF_SV);
  float* biasc   = (float*)(ws + OFF_BIASC);
  float* h_all   = (float*)(ws + OFF_HALL);
  float* ldbuf   = (float*)(ws + OFF_LD);
  f16*   Wc2     = (f16*)  (ws + OFF_WC2);
  f16*   rnn     = (f16*)  (ws + OFF_RNN);
  f16*   outw    = (f16*)  (ws + OFF_OUTW);

  float* outp  = (float*)d_out;          // (256,128)
  float* dists = outp + 256 * 128;       // (50,256)

  // phase 0: prep
  k_gather     <<<25600, 256, 0, stream>>>(node_ids, embed, xf);
  k_prep_wk    <<<26624, 256, 0, stream>>>(kernel_w, kernel_b, rec_b, Wk, biasc);
  k_prep_rwpack<<<147,   512, 0, stream>>>(rec_w, kernel_w, RWp, Sv);
  k_prep_scale <<<192,   256, 0, stream>>>(scale_w, scale_b, rescale_w, swp, sbp, rwp2);
  k_prep_wc    <<<5760,  256, 0, stream>>>(conv_w, Wc2);
  // phase 1: XKh = f16( x @ kernel_w^T + (kernel_b + rec_b) )
  k_gemm_bt<<<dim3(100, 13), 256, 0, stream>>>(xf, Wk, XKh, biasc, GP, 4096, 4096, 1);
  // phase 2: cooperative weights-stationary recurrence
  {
    void* cargs[] = {(void*)&XKh, (void*)&RWp, (void*)&Sv, (void*)&timep,
                     (void*)&xo_g, (void*)&hext_g, (void*)&h_all, (void*)&dists};
    hipLaunchCooperativeKernel((void*)k_recur_coop, dim3(32), dim3(512), cargs, 0, stream);
  }
  // phase 3: deferred outputs (fully parallel)
  k_ld  <<<50,    256, 0, stream>>>(dists, ldbuf);
  k_lh  <<<24000, 256, 0, stream>>>(ldbuf, h_all, lh);
  k_mlh <<<19200, 256, 0, stream>>>(ldbuf, h_all, mlh_h);
  k_gemm_bt<<<dim3(100, 1), 256, 0, stream>>>(mlh_h, swp, s1h, sbp, 128, 384, 384, 2);
  k_gemm_bt<<<dim3(100, 3), 256, 0, stream>>>(s1h, rwp2, theme, rescale_b, 384, 128, 128, 3);
  k_gemm_bt<<<dim3(100, 3), 256, 0, stream>>>(lh, Wc2, convbuf, conv_b, 384, KH, KH, 0);
  k_rnn <<<19200, 256, 0, stream>>>(theme, convbuf, h_all, rnn);
  k_cvt <<<9600,  256, 0, stream>>>(out_w, outw, 128L * KO);
  // phase 4: out = rnn @ out_w^T + out_b   (K split 8 ways, then reduce)
  k_gemm_bt<<<dim3(2, 1, 8), 256, 0, stream>>>(rnn, outw, opart, nullptr, 128, KO, KO / 8, 0);
  k_red8<<<128, 256, 0, stream>>>(opart, out_b, outp);
}

// Round 7
// 1865.417 us; speedup vs baseline: 1.4441x; 1.0435x over previous
//
#include <hip/hip_runtime.h>
#include <math.h>

// ---------------- types ----------------
typedef _Float16 f16;
typedef _Float16 f16x8 __attribute__((ext_vector_type(8)));
typedef float f32x4 __attribute__((ext_vector_type(4)));

#define DEV static __device__ __forceinline__

DEV float sigm(float x)  { return 1.0f / (1.0f + __expf(-x)); }
DEV float tanhfast(float x) { return 2.0f / (1.0f + __expf(-2.0f * x)) - 1.0f; }

// async global->LDS, 16B per lane (dest must be wave-uniform base + lane*16)
DEV void gld16(const void* g, void* l) {
  __builtin_amdgcn_global_load_lds((const __attribute__((address_space(1))) void*)g,
                                   (__attribute__((address_space(3))) void*)l, 16, 0, 0);
}

// lightweight device-wide barrier (all NBLK blocks co-resident via cooperative launch)
DEV void gbar(int* bar, int nblk) {
  __syncthreads();
  if (threadIdx.x == 0) {
    __threadfence();   // release prior global writes (wbl2)
    int* cnt = bar;
    int* gen = bar + 16;
    int g = __hip_atomic_load(gen, __ATOMIC_RELAXED, __HIP_MEMORY_SCOPE_AGENT);
    int a = __hip_atomic_fetch_add(cnt, 1, __ATOMIC_ACQ_REL, __HIP_MEMORY_SCOPE_AGENT);
    if (a == nblk - 1) {
      __hip_atomic_store(cnt, 0, __ATOMIC_RELAXED, __HIP_MEMORY_SCOPE_AGENT);
      __hip_atomic_store(gen, g + 1, __ATOMIC_RELEASE, __HIP_MEMORY_SCOPE_AGENT);
    } else {
      while (__hip_atomic_load(gen, __ATOMIC_ACQUIRE, __HIP_MEMORY_SCOPE_AGENT) == g)
        __builtin_amdgcn_s_sleep(1);
    }
    __threadfence();   // acquire (inv) before consuming peers' writes
  }
  __syncthreads();
}

// ---------------- problem constants ----------------
// B=256 V=50 N=32 D=128 H=384 L=12 CS=10 ND=4096 G=1560 OUT=128
#define GP 1664   // padded G (13*128) — XK gemm N and XKh row stride
#define XOG 1568  // xo global row stride (f16); 98 tiles cover cols 0..1567
#define KH 3840   // H*CS (conv gemm K)
#define KO 19200  // V*H  (out gemm K)
#define NBLK 32

// ---------------- workspace layout (bytes) ----------------
static constexpr size_t OFF_X     = 0;                       // xf 104857600; lh/opart alias later
static constexpr size_t OFF_LH    = 0;
static constexpr size_t OFF_OPART = 0;
// k_recur-only aliases inside the (dead during recur) xf region:
static constexpr size_t OFF_XOG   = 0;                       // xo_g f16 256*1568*2 = 802816
static constexpr size_t OFF_HEXT  = 1048576;                 // hext_g f16 256*384*2 = 196608
static constexpr size_t OFF_WK    = 104857600;               // 13631488
static constexpr size_t OFF_XK    = OFF_WK + 13631488;       // XKh f16 12800*1664*2 = 42598400
// aliases of the XK region (XKh dead after k_recur):
static constexpr size_t OFF_MLH   = OFF_XK;                  // mlh_h f16 9830400
static constexpr size_t OFF_S1    = OFF_XK + 9830400;        // s1h f16 3276800
static constexpr size_t OFF_TH    = OFF_XK + 13107200;       // theme f32 19660800
static constexpr size_t OFF_CV    = OFF_XK + 32768000;       // conv f32 19660800 (ends +52428800)
static constexpr size_t OFF_SWP   = OFF_XK + 52428800;       // swp f16 98304 (> XKh end)
static constexpr size_t OFF_RWP2  = OFF_XK + 52527104;       // rwp2 f16 98304
static constexpr size_t OFF_SBP   = OFF_XK + 52625408;       // sbp f32 512
static constexpr size_t OFF_RW    = OFF_XK + 85196800;       // RWpack f16 1204224 B
static constexpr size_t OFF_SV    = OFF_RW + 1277952;        // Sv f32 6656
static constexpr size_t OFF_BAR   = OFF_RW + 1302528;        // barrier cnt/gen (128 B)
static constexpr size_t OFF_BIASC = OFF_RW + 1384448;        // 8192
static constexpr size_t OFF_HALL  = OFF_BIASC + 8192;        // h_all f32 19660800
static constexpr size_t OFF_LD    = OFF_HALL + 19660800;     // 512000
static constexpr size_t OFF_WC2   = OFF_LD + 512000;         // 2949120
static constexpr size_t OFF_RNN   = OFF_WC2 + 2949120;       // 9830400
static constexpr size_t OFF_OUTW  = OFF_RNN + 9830400;       // 4915200

// ---------------- kernels ----------------

// embedding gather -> x_f16 (12800 x 4096), 8 halfs / thread
__global__ __launch_bounds__(256) void k_gather(const int* __restrict__ ids,
                                                const float* __restrict__ embed,
                                                f16* __restrict__ xf) {
  int i = blockIdx.x * 256 + threadIdx.x;     // 12800*512 total
  int row = i >> 9;
  int c8  = i & 511;
  int n = c8 >> 4;
  int d = (c8 & 15) << 3;
  int id = ids[row * 32 + n];
  const float* e = embed + (long)id * 128 + d;
  float4 a = *(const float4*)e;
  float4 b = *(const float4*)(e + 4);
  f16x8 o;
  o[0]=(f16)a.x; o[1]=(f16)a.y; o[2]=(f16)a.z; o[3]=(f16)a.w;
  o[4]=(f16)b.x; o[5]=(f16)b.y; o[6]=(f16)b.z; o[7]=(f16)b.w;
  *(f16x8*)(xf + ((long)row << 12) + (c8 << 3)) = o;
}

// kernel_w (1560 x 4097) -> Wk_f16 (1664 x 4096, zero-padded rows); biasc = kb+rb (padded 1664)
__global__ __launch_bounds__(256) void k_prep_wk(const float* __restrict__ kw,
                                                 const float* __restrict__ kb,
                                                 const float* __restrict__ rb,
                                                 f16* __restrict__ Wk,
                                                 float* __restrict__ biasc) {
  long i = (long)blockIdx.x * 256 + threadIdx.x;
  if (i < 1664L * 4096) {
    int nn = (int)(i >> 12);
    int k  = (int)(i & 4095);
    float v = (nn < 1560) ? kw[(long)nn * 4097 + k] : 0.0f;
    Wk[i] = (f16)v;
  }
  if (i < 1664) biasc[i] = (i < 1560) ? (kb[i] + rb[i]) : 0.0f;
}

// rec_w (1560x385) -> RWpack per-lane MFMA B-fragment order; Sv; zero barrier state.
__global__ __launch_bounds__(512) void k_prep_rwpack(const float* __restrict__ rw,
                                                     const float* __restrict__ kw,
                                                     f16* __restrict__ RWp,
                                                     float* __restrict__ Sv,
                                                     int* __restrict__ bar) {
  int i = blockIdx.x * 512 + threadIdx.x;      // 98*12*64 = 75264 chunks of 8 halfs
  if (i < 75264) {
    int nt = i / 768;
    int rem = i - nt * 768;
    int f = rem >> 6;
    int l = rem & 63;
    int row = nt * 16 + (l & 15);
    int k = f * 32 + ((l >> 4) << 3);
    f16x8 o;
    if (row < 1560) {
      const float* s = rw + (long)row * 385 + k;
#pragma unroll
      for (int e = 0; e < 8; ++e) o[e] = (f16)s[e];
    } else {
#pragma unroll
      for (int e = 0; e < 8; ++e) o[e] = (f16)0.0f;
    }
    *(f16x8*)(RWp + (long)i * 8) = o;
  }
  if (i < 1664)
    Sv[i] = (i < 1560) ? (rw[(long)i * 385 + 384] + kw[(long)i * 4097 + 4096]) : 0.0f;
  if (i < 32) bar[i] = 0;
}

// conv_w (384,384,10) -> Wc2_f16[o][j*384+h]
__global__ __launch_bounds__(256) void k_prep_wc(const float* __restrict__ cw,
                                                 f16* __restrict__ Wc2) {
  int i = blockIdx.x * 256 + threadIdx.x;     // 384*3840
  if (i >= 384 * 3840) return;
  int o = i / 3840;
  int c = i - o * 3840;
  int j = c / 384;
  int h = c - j * 384;
  Wc2[i] = (f16)cw[((long)o * 384 + h) * 10 + j];
}

// scale_w (64,384)->swp(128,384,f16,zero-pad rows); scale_b->sbp(128); rescale_w(384,64)->rwp2(384,128,zero-pad cols)
__global__ __launch_bounds__(256) void k_prep_scale(const float* __restrict__ sw,
                                                    const float* __restrict__ sb,
                                                    const float* __restrict__ rw2,
                                                    f16* __restrict__ swp,
                                                    float* __restrict__ sbp,
                                                    f16* __restrict__ rwp2) {
  int i = blockIdx.x * 256 + threadIdx.x;   // 49152
  if (i < 128 * 384) {
    int o = i / 384, k = i - o * 384;
    swp[i] = (f16)((o < 64) ? sw[o * 384 + k] : 0.0f);
    int o2 = i >> 7, k2 = i & 127;
    rwp2[i] = (f16)((k2 < 64) ? rw2[o2 * 64 + k2] : 0.0f);
  }
  if (i < 128) sbp[i] = (i < 64) ? sb[i] : 0.0f;
}

// generic fp32 -> f16 convert
__global__ __launch_bounds__(256) void k_cvt(const float* __restrict__ src,
                                             f16* __restrict__ dst, long n) {
  long i = (long)blockIdx.x * 256 + threadIdx.x;
  if (i < n) dst[i] = (f16)src[i];
}

// C = A(M x K) * W(N x K)^T (+bias[col]); m97-style global_load_lds staging.
// grid.z splits K (writes partials at z*M*N). act: 0=f32, 1=f16, 2=relu->f16, 3=sigmoid->f32.
__global__ __launch_bounds__(256) void k_gemm_bt(const f16* __restrict__ A,
                                                 const f16* __restrict__ W,
                                                 void* __restrict__ Cv,
                                                 const float* __restrict__ bias,
                                                 int N, int K, int kLen, int act) {
  __shared__ __align__(16) f16 As[128 * 32];   // unpadded: global_load_lds needs lane-contiguous dest
  __shared__ __align__(16) f16 Bs[128 * 32];
  const int tid = threadIdx.x;
  const long rowA0 = (long)blockIdx.x * 128;
  const long rowB0 = (long)blockIdx.y * 128;
  const long ks = (long)blockIdx.z * kLen;
  const long zoff = (long)blockIdx.z * ((long)gridDim.x * 128 * N);
  const int w = tid >> 6, lane = tid & 63;
  const int q = lane >> 4, r16 = lane & 15;
  const int wr = w >> 1, wc = w & 1;
  f32x4 acc[4][4] = {};
  const int srow = tid >> 2;
  const int scol = (tid & 3) * 8;
  const f16* gA0 = A + (rowA0 + srow) * (long)K + ks + scol;
  const f16* gA1 = gA0 + 64L * K;
  const f16* gB0 = W + (rowB0 + srow) * (long)K + ks + scol;
  const f16* gB1 = gB0 + 64L * K;
  f16* lA = As + tid * 8;
  f16* lB = Bs + tid * 8;
  for (int k0 = 0; k0 < kLen; k0 += 32) {
    __syncthreads();
    gld16(gA0 + k0, lA);
    gld16(gA1 + k0, lA + 2048);
    gld16(gB0 + k0, lB);
    gld16(gB1 + k0, lB + 2048);
    __syncthreads();
    f16x8 af[4], bfr[4];
#pragma unroll
    for (int i = 0; i < 4; i++) {
      af[i]  = *(const f16x8*)&As[(wr * 64 + i * 16 + r16) * 32 + q * 8];
      bfr[i] = *(const f16x8*)&Bs[(wc * 64 + i * 16 + r16) * 32 + q * 8];
    }
#pragma unroll
    for (int i = 0; i < 4; i++)
#pragma unroll
      for (int j = 0; j < 4; j++)
        acc[i][j] = __builtin_amdgcn_mfma_f32_16x16x32_f16(af[i], bfr[j], acc[i][j], 0, 0, 0);
  }
#pragma unroll
  for (int i = 0; i < 4; i++)
#pragma unroll
    for (int j = 0; j < 4; j++) {
      long row = rowA0 + wr * 64 + i * 16 + q * 4;
      long col = rowB0 + wc * 64 + j * 16 + r16;
      float bv = bias ? bias[col] : 0.0f;
#pragma unroll
      for (int r = 0; r < 4; r++) {
        float v = acc[i][j][r] + bv;
        long off = (row + r) * (long)N + col + zoff;
        if (act == 0)      ((float*)Cv)[off] = v;
        else if (act == 1) ((f16*)Cv)[off]   = (f16)v;
        else if (act == 2) ((f16*)Cv)[off]   = (f16)fmaxf(v, 0.0f);
        else               ((float*)Cv)[off] = sigm(v);
      }
    }
}

// cooperative weights-stationary recurrence: 32 blocks x 512 threads.
// Block owns 3-4 N-tiles of RW in LDS for the whole kernel. Per step:
// GEMM N-slice over all 256 batches -> fast device barrier -> gates (8 batches/block)
// -> fast device barrier.
__global__ __launch_bounds__(512)
void k_recur_coop(const f16* __restrict__ XKh,    // (12800,1664) f16, bias folded
                  const f16* __restrict__ RWp,    // packed (98,12,64,8) f16
                  const float* __restrict__ Sv,   // (1664)
                  const float* __restrict__ timep,// (256,50)
                  f16* __restrict__ xo_g,         // (256, XOG)
                  f16* __restrict__ hext_g,       // (256, 384)
                  float* __restrict__ h_all,      // (50,256,384)
                  float* __restrict__ dists,      // (50,256)
                  int* __restrict__ bar) {
  __shared__ __align__(16) f16 Wl[4 * 6144];      // up to 4 tiles, fragment order (49152 B)
  __shared__ float Svl[1568];                     // 6272 B
  const int tid = threadIdx.x;
  const int bid = blockIdx.x;
  const int w = tid >> 6, lane = tid & 63;
  const int q = lane >> 4, r16 = lane & 15;
  const int T = (bid < 2) ? 4 : 3;                        // 2*4 + 30*3 = 98 tiles
  const int tstart = (bid < 2) ? bid * 4 : 8 + (bid - 2) * 3;
  // stationary weights -> LDS (once)
  {
    const f16* src = RWp + (size_t)tstart * 6144;
    for (int i = tid; i < T * 768; i += 512)
      *(f16x8*)(Wl + (size_t)i * 8) = *(const f16x8*)(src + (size_t)i * 8);
  }
  for (int i = tid; i < 1568; i += 512) Svl[i] = Sv[i];
  // zero h_ext globally (grid-strided)
  {
    f16x8 z = {};
    for (int i = bid * 512 + tid; i < 12288; i += 32 * 512)
      *(f16x8*)(hext_g + (size_t)i * 8) = z;
  }
  gbar(bar, NBLK);

  // gate mapping: thread = (batch gm 0..7, half 0..1, channel gch 0..31)
  const int gm = tid >> 6;
  const int ghalf = (tid >> 5) & 1;
  const int gch = tid & 31;
  const int gl0 = ghalf * 6;
  const int gb = bid * 8 + gm;
  float creg[6] = {};

  for (int t = 0; t < 50; ++t) {
    // ---- GEMM phase: wave w -> M-tiles {2w, 2w+1}, all T local N-tiles ----
#pragma unroll
    for (int mi = 0; mi < 2; ++mi) {
      const int rowb = (w * 2 + mi) * 16;         // batch base of this M-tile
      f16x8 af[12];
      const f16* ab = hext_g + (size_t)(rowb + r16) * 384 + q * 8;
#pragma unroll
      for (int f = 0; f < 12; ++f) af[f] = *(const f16x8*)(ab + f * 32);
      float tv4[4];
#pragma unroll
      for (int r = 0; r < 4; ++r) tv4[r] = timep[(rowb + q * 4 + r) * 50 + t];
      f16 xk[4][4];
#pragma unroll
      for (int j = 0; j < 4; ++j) if (j < T) {
        const int c0 = (tstart + j) * 16;
#pragma unroll
        for (int r = 0; r < 4; ++r)
          xk[j][r] = XKh[((long)(rowb + q * 4 + r) * 50 + t) * GP + c0 + r16];
      }
#pragma unroll
      for (int j = 0; j < 4; ++j) if (j < T) {
        const int c0 = (tstart + j) * 16;
        const f16* bp = Wl + j * 6144 + lane * 8;
        f32x4 a0 = {};
#pragma unroll
        for (int f = 0; f < 12; ++f)
          a0 = __builtin_amdgcn_mfma_f32_16x16x32_f16(af[f], *(const f16x8*)(bp + f * 512), a0, 0, 0, 0);
        const float Svc = Svl[c0 + r16];
#pragma unroll
        for (int r = 0; r < 4; ++r)
          xo_g[(size_t)(rowb + q * 4 + r) * XOG + c0 + r16] = (f16)(a0[r] + (float)xk[j][r] + tv4[r] * Svc);
      }
    }
    gbar(bar, NBLK);   // xo ready everywhere
    // ---- gate phase: all 32 blocks, 8 batches each ----
    {
      const f16* xom = xo_g + (size_t)gb * XOG;
      float fm[12], im[12];
      {
        float v1[12], v2[12], mx1 = -1e30f, mx2 = -1e30f;
#pragma unroll
        for (int l = 0; l < 12; l++) {
          v1[l] = (float)xom[l];      mx1 = fmaxf(mx1, v1[l]);
          v2[l] = (float)xom[12 + l]; mx2 = fmaxf(mx2, v2[l]);
        }
        float s1 = 0.0f, s2 = 0.0f;
#pragma unroll
        for (int l = 0; l < 12; l++) {
          v1[l] = __expf(v1[l] - mx1); s1 += v1[l];
          v2[l] = __expf(v2[l] - mx2); s2 += v2[l];
        }
        float i1 = 1.0f / s1, i2 = 1.0f / s2, c1 = 0.0f, c2 = 0.0f;
#pragma unroll
        for (int l = 0; l < 12; l++) { c1 += v1[l]; fm[l] = c1 * i1; }
#pragma unroll
        for (int l = 11; l >= 0; l--) { c2 += v2[l]; im[l] = c2 * i2; }
      }
      if (ghalf == 0 && gch == 0) {
        float ds = 0.0f;
#pragma unroll
        for (int l = 0; l < 12; l++) ds += fm[l];
        dists[t * 256 + gb] = 1.0f - ds * (1.0f / 12.0f);
      }
      float* hdst = h_all + ((long)t * 256 + gb) * 384;
#pragma unroll
      for (int j = 0; j < 6; j++) {
        const int l = gl0 + j;
        float fv = sigm((float)xom[24 + l * 32 + gch]);
        float iv = sigm((float)xom[24 + (12 + l) * 32 + gch]);
        float og = sigm((float)xom[24 + (24 + l) * 32 + gch]);
        float ci = tanhfast((float)xom[24 + (36 + l) * 32 + gch]);
        float fmv = fm[l], imv = im[l], ov = fmv * imv;
        float cn = ov * (fv * creg[j] + iv * ci) + (fmv - ov) * creg[j] + (imv - ov) * ci;
        creg[j] = cn;
        float hv = og * tanhfast(cn);
        hdst[l * 32 + gch] = hv;
        hext_g[(size_t)gb * 384 + l * 32 + gch] = (f16)hv;
      }
    }
    gbar(bar, NBLK);   // h_ext(t) visible for GEMM(t+1)
  }
}

// ld[b,t,:] = softmax_j(cumsum_j dist[t-9+j])
__global__ __launch_bounds__(256) void k_ld(const float* __restrict__ dists,
                                            float* __restrict__ ld) {
  int i = blockIdx.x * 256 + threadIdx.x;
  if (i >= 12800) return;
  int b = i / 50, t = i - b * 50;
  float v[10];
  float cum = 0.0f, mx = -1e30f;
#pragma unroll
  for (int j = 0; j < 10; j++) {
    int s = t - 9 + j;
    float d = (s >= 0) ? dists[s * 256 + b] : 0.0f;
    cum += d; v[j] = cum; mx = fmaxf(mx, cum);
  }
  float sum = 0.0f;
#pragma unroll
  for (int j = 0; j < 10; j++) { v[j] = __expf(v[j] - mx); sum += v[j]; }
  float inv = 1.0f / sum;
#pragma unroll
  for (int j = 0; j < 10; j++) ld[i * 10 + j] = v[j] * inv;
}

// lh_f16[(b,t)][j*384+h] = ld[b,t,j] * h_{t-9+j}[b,h]
__global__ __launch_bounds__(256) void k_lh(const float* __restrict__ ld,
                                            const float* __restrict__ h_all,
                                            f16* __restrict__ lh) {
  int i = blockIdx.x * 256 + threadIdx.x;   // 12800*480
  int row = i / 480;
  int c = i - row * 480;
  int j = c / 48;
  int h0 = (c - j * 48) * 8;
  int b = row / 50, t = row - b * 50;
  int s = t - 9 + j;
  f16x8 o;
  if (s >= 0) {
    float wv = ld[row * 10 + j];
    const float* hp = h_all + ((long)s * 256 + b) * 384 + h0;
#pragma unroll
    for (int k = 0; k < 8; k++) o[k] = (f16)(wv * hp[k]);
  } else {
#pragma unroll
    for (int k = 0; k < 8; k++) o[k] = (f16)0.0f;
  }
  *(f16x8*)(lh + (long)row * KH + j * 384 + h0) = o;
}

// mlh_h[(b,t)][h] = mean_j (f16)
__global__ __launch_bounds__(256) void k_mlh(const float* __restrict__ ld,
                                             const float* __restrict__ h_all,
                                             f16* __restrict__ mlh) {
  int i = blockIdx.x * 256 + threadIdx.x;   // 12800*384
  int row = i / 384, h = i - row * 384;
  int b = row / 50, t = row - b * 50;
  float acc = 0.0f;
#pragma unroll
  for (int j = 0; j < 10; j++) {
    int s = t - 9 + j;
    if (s >= 0) acc += ld[row * 10 + j] * h_all[((long)s * 256 + b) * 384 + h];
  }
  mlh[i] = (f16)(acc * 0.1f);
}

// rnn_f16[b][t*384+h] = theme*conv + h
__global__ __launch_bounds__(256) void k_rnn(const float* __restrict__ theme,
                                             const float* __restrict__ conv,
                                             const float* __restrict__ h_all,
                                             f16* __restrict__ rnn) {
  int i = blockIdx.x * 256 + threadIdx.x;   // 12800*384, ordered (b,t,h)
  int row = i / 384, h = i - row * 384;
  int b = row / 50, t = row - b * 50;
  float local = theme[i] * conv[i];
  float hv = h_all[((long)t * 256 + b) * 384 + h];
  rnn[i] = (f16)(local + hv);               // (b*50+t)*384+h == b*19200 + t*384 + h
}

// out[i] = sum_z part[z][i] + out_b
__global__ __launch_bounds__(256) void k_red8(const float* __restrict__ part,
                                              const float* __restrict__ ob,
                                              float* __restrict__ out) {
  int i = blockIdx.x * 256 + threadIdx.x;   // 32768
  float s = 0.0f;
#pragma unroll
  for (int z = 0; z < 8; z++) s += part[z * 32768 + i];
  out[i] = s + ob[i & 127];
}

// ---------------- launch ----------------
extern "C" void kernel_launch(void* const* d_in, const int* in_sizes, int n_in,
                              void* d_out, int out_size, void* d_ws, size_t ws_size,
                              hipStream_t stream) {
  (void)in_sizes; (void)n_in; (void)out_size; (void)ws_size;
  const int*   node_ids  = (const int*)  d_in[0];
  const float* timep     = (const float*)d_in[3];
  const float* embed     = (const float*)d_in[6];
  const float* kernel_w  = (const float*)d_in[7];
  const float* kernel_b  = (const float*)d_in[8];
  const float* rec_w     = (const float*)d_in[9];
  const float* rec_b     = (const float*)d_in[10];
  const float* scale_w   = (const float*)d_in[11];
  const float* scale_b   = (const float*)d_in[12];
  const float* rescale_w = (const float*)d_in[13];
  const float* rescale_b = (const float*)d_in[14];
  const float* conv_w    = (const float*)d_in[15];
  const float* conv_b    = (const float*)d_in[16];
  const float* out_w     = (const float*)d_in[17];
  const float* out_b     = (const float*)d_in[18];

  char* ws = (char*)d_ws;
  f16*   xf      = (f16*)  (ws + OFF_X);
  f16*   lh      = (f16*)  (ws + OFF_LH);
  float* opart   = (float*)(ws + OFF_OPART);
  f16*   xo_g    = (f16*)  (ws + OFF_XOG);
  f16*   hext_g  = (f16*)  (ws + OFF_HEXT);
  f16*   Wk      = (f16*)  (ws + OFF_WK);
  f16*   XKh     = (f16*)  (ws + OFF_XK);
  f16*   mlh_h   = (f16*)  (ws + OFF_MLH);
  f16*   s1h     = (f16*)  (ws + OFF_S1);
  float* theme   = (float*)(ws + OFF_TH);
  float* convbuf = (float*)(ws + OFF_CV);
  f16*   swp     = (f16*)  (ws + OFF_SWP);
  f16*   rwp2    = (f16*)  (ws + OFF_RWP2);
  float* sbp     = (float*)(ws + OFF_SBP);
  f16*   RWp     = (f16*)  (ws + OFF_RW);
  float* Sv      = (float*)(ws + OFF_SV);
  int*   bar     = (int*)  (ws + OFF_BAR);
  float* biasc   = (float*)(ws + OFF_BIASC);
  float* h_all   = (float*)(ws + OFF_HALL);
  float* ldbuf   = (float*)(ws + OFF_LD);
  f16*   Wc2     = (f16*)  (ws + OFF_WC2);
  f16*   rnn     = (f16*)  (ws + OFF_RNN);
  f16*   outw    = (f16*)  (ws + OFF_OUTW);

  float* outp  = (float*)d_out;          // (256,128)
  float* dists = outp + 256 * 128;       // (50,256)

  // phase 0: prep
  k_gather     <<<25600, 256, 0, stream>>>(node_ids, embed, xf);
  k_prep_wk    <<<26624, 256, 0, stream>>>(kernel_w, kernel_b, rec_b, Wk, biasc);
  k_prep_rwpack<<<147,   512, 0, stream>>>(rec_w, kernel_w, RWp, Sv, bar);
  k_prep_scale <<<192,   256, 0, stream>>>(scale_w, scale_b, rescale_w, swp, sbp, rwp2);
  k_prep_wc    <<<5760,  256, 0, stream>>>(conv_w, Wc2);
  // phase 1: XKh = f16( x @ kernel_w^T + (kernel_b + rec_b) )
  k_gemm_bt<<<dim3(100, 13), 256, 0, stream>>>(xf, Wk, XKh, biasc, GP, 4096, 4096, 1);
  // phase 2: cooperative weights-stationary recurrence (fast device barrier)
  {
    void* cargs[] = {(void*)&XKh, (void*)&RWp, (void*)&Sv, (void*)&timep,
                     (void*)&xo_g, (void*)&hext_g, (void*)&h_all, (void*)&dists,
                     (void*)&bar};
    hipLaunchCooperativeKernel((void*)k_recur_coop, dim3(NBLK), dim3(512), cargs, 0, stream);
  }
  // phase 3: deferred outputs (fully parallel)
  k_ld  <<<50,    256, 0, stream>>>(dists, ldbuf);
  k_lh  <<<24000, 256, 0, stream>>>(ldbuf, h_all, lh);
  k_mlh <<<19200, 256, 0, stream>>>(ldbuf, h_all, mlh_h);
  k_gemm_bt<<<dim3(100, 1), 256, 0, stream>>>(mlh_h, swp, s1h, sbp, 128, 384, 384, 2);
  k_gemm_bt<<<dim3(100, 3), 256, 0, stream>>>(s1h, rwp2, theme, rescale_b, 384, 128, 128, 3);
  k_gemm_bt<<<dim3(100, 3), 256, 0, stream>>>(lh, Wc2, convbuf, conv_b, 384, KH, KH, 0);
  k_rnn <<<19200, 256, 0, stream>>>(theme, convbuf, h_all, rnn);
  k_cvt <<<9600,  256, 0, stream>>>(out_w, outw, 128L * KO);
  // phase 4: out = rnn @ out_w^T + out_b   (K split 8 ways, then reduce)
  k_gemm_bt<<<dim3(2, 1, 8), 256, 0, stream>>>(rnn, outw, opart, nullptr, 128, KO, KO / 8, 0);
  k_red8<<<128, 256, 0, stream>>>(opart, out_b, outp);
}

// Round 9
// 1379.383 us; speedup vs baseline: 1.9529x; 1.3524x over previous
//
#include <hip/hip_runtime.h>
#include <math.h>

// ---------------- types ----------------
typedef _Float16 f16;
typedef _Float16 f16x8 __attribute__((ext_vector_type(8)));
typedef float f32x4 __attribute__((ext_vector_type(4)));

#define DEV static __device__ __forceinline__

DEV float sigm(float x)  { return 1.0f / (1.0f + __expf(-x)); }
DEV float tanhfast(float x) { return 2.0f / (1.0f + __expf(-2.0f * x)) - 1.0f; }

// async global->LDS, 16B per lane (dest must be wave-uniform base + lane*16)
DEV void gld16(const void* g, void* l) {
  __builtin_amdgcn_global_load_lds((const __attribute__((address_space(1))) void*)g,
                                   (__attribute__((address_space(3))) void*)l, 16, 0, 0);
}

// minimal-fence group barrier. Release rides the arrival RMW (wbl2 of this XCD's
// dirty lines); spin is RELAXED (no per-poll L2 invalidate); single ACQUIRE load
// on exit (one inv). HW-sound: peers' wbl2 precede their arrival increments, so
// observing the flip + our inv guarantees fresh reads from LLC.
DEV void gbar(int* bar, int nblk) {
  __syncthreads();
  if (threadIdx.x == 0) {
    int* cnt = bar;
    int* gen = bar + 16;
    int g = __hip_atomic_load(gen, __ATOMIC_RELAXED, __HIP_MEMORY_SCOPE_AGENT);
    int a = __hip_atomic_fetch_add(cnt, 1, __ATOMIC_RELEASE, __HIP_MEMORY_SCOPE_AGENT);
    if (a == nblk - 1) {
      __hip_atomic_store(cnt, 0, __ATOMIC_RELAXED, __HIP_MEMORY_SCOPE_AGENT);
      __hip_atomic_store(gen, g + 1, __ATOMIC_RELEASE, __HIP_MEMORY_SCOPE_AGENT);
    } else {
      while (__hip_atomic_load(gen, __ATOMIC_RELAXED, __HIP_MEMORY_SCOPE_AGENT) == g)
        __builtin_amdgcn_s_sleep(1);
    }
    (void)__hip_atomic_load(gen, __ATOMIC_ACQUIRE, __HIP_MEMORY_SCOPE_AGENT); // single inv
  }
  __syncthreads();
}

// ---------------- problem constants ----------------
// B=256 V=50 N=32 D=128 H=384 L=12 CS=10 ND=4096 G=1560 OUT=128
#define GP 1664   // padded G (13*128) — XK gemm N and XKh row stride
#define XOG 1568  // xo global row stride (f16); 98 tiles cover cols 0..1567
#define KH 3840   // H*CS (conv gemm K)
#define KO 19200  // V*H  (out gemm K)
// recurrence: 8 groups (1/XCD under round-robin) x 8 member blocks
#define NGRP 8
#define NMEM 8
// dynamic LDS: 13 tiles x 12288 B + Sv slice (13*16 f32)
#define RECUR_LDS (159744 + 832)

// ---------------- workspace layout (bytes) ----------------
static constexpr size_t OFF_X     = 0;                       // xf 104857600; lh/opart alias later
static constexpr size_t OFF_LH    = 0;
static constexpr size_t OFF_OPART = 0;                       // out partials 8*32768*4 = 1048576
// k_recur-only aliases inside the (dead during recur) xf region:
static constexpr size_t OFF_XOG   = 0;                       // xo_g f16 256*1568*2 = 802816
static constexpr size_t OFF_HEXT  = 1048576;                 // hext_g f16 256*384*2 = 196608
static constexpr size_t OFF_WK    = 104857600;               // 13631488
static constexpr size_t OFF_XK    = OFF_WK + 13631488;       // XKh f16 12800*1664*2 = 42598400
// aliases of the XK region (XKh dead after k_recur):
static constexpr size_t OFF_MLH   = OFF_XK;                  // mlh_h f16 9830400
static constexpr size_t OFF_S1    = OFF_XK + 9830400;        // s1h f16 3276800
static constexpr size_t OFF_TH    = OFF_XK + 13107200;       // theme f32 19660800
static constexpr size_t OFF_CV    = OFF_XK + 32768000;       // conv partials 2x19660800 B (ends +72089600)
static constexpr size_t OFF_SWP   = OFF_XK + 72089600;       // swp f16 98304
static constexpr size_t OFF_RWP2  = OFF_XK + 72187904;       // rwp2 f16 98304
static constexpr size_t OFF_SBP   = OFF_XK + 72286208;       // sbp f32 512
static constexpr size_t OFF_RW    = OFF_XK + 85196800;       // RWpack f16 1204224 B
static constexpr size_t OFF_SV    = OFF_RW + 1277952;        // Sv f32 6656
static constexpr size_t OFF_BAR   = OFF_RW + 1302528;        // barrier state: 8 groups x 32 ints
static constexpr size_t OFF_BIASC = OFF_RW + 1384448;        // 8192
static constexpr size_t OFF_HALL  = OFF_BIASC + 8192;        // h_all f32 19660800
static constexpr size_t OFF_LD    = OFF_HALL + 19660800;     // 512000
static constexpr size_t OFF_WC2   = OFF_LD + 512000;         // 2949120
static constexpr size_t OFF_RNN   = OFF_WC2 + 2949120;       // 9830400
static constexpr size_t OFF_OUTW  = OFF_RNN + 9830400;       // 4915200

// ---------------- kernels ----------------

// embedding gather -> x_f16 (12800 x 4096), 8 halfs / thread
__global__ __launch_bounds__(256) void k_gather(const int* __restrict__ ids,
                                                const float* __restrict__ embed,
                                                f16* __restrict__ xf) {
  int i = blockIdx.x * 256 + threadIdx.x;     // 12800*512 total
  int row = i >> 9;
  int c8  = i & 511;
  int n = c8 >> 4;
  int d = (c8 & 15) << 3;
  int id = ids[row * 32 + n];
  const float* e = embed + (long)id * 128 + d;
  float4 a = *(const float4*)e;
  float4 b = *(const float4*)(e + 4);
  f16x8 o;
  o[0]=(f16)a.x; o[1]=(f16)a.y; o[2]=(f16)a.z; o[3]=(f16)a.w;
  o[4]=(f16)b.x; o[5]=(f16)b.y; o[6]=(f16)b.z; o[7]=(f16)b.w;
  *(f16x8*)(xf + ((long)row << 12) + (c8 << 3)) = o;
}

// kernel_w (1560 x 4097) -> Wk_f16 (1664 x 4096, zero-padded rows); biasc = kb+rb (padded 1664)
__global__ __launch_bounds__(256) void k_prep_wk(const float* __restrict__ kw,
                                                 const float* __restrict__ kb,
                                                 const float* __restrict__ rb,
                                                 f16* __restrict__ Wk,
                                                 float* __restrict__ biasc) {
  long i = (long)blockIdx.x * 256 + threadIdx.x;
  if (i < 1664L * 4096) {
    int nn = (int)(i >> 12);
    int k  = (int)(i & 4095);
    float v = (nn < 1560) ? kw[(long)nn * 4097 + k] : 0.0f;
    Wk[i] = (f16)v;
  }
  if (i < 1664) biasc[i] = (i < 1560) ? (kb[i] + rb[i]) : 0.0f;
}

// rec_w (1560x385) -> RWpack per-lane MFMA B-fragment order; Sv; zero barrier state.
__global__ __launch_bounds__(512) void k_prep_rwpack(const float* __restrict__ rw,
                                                     const float* __restrict__ kw,
                                                     f16* __restrict__ RWp,
                                                     float* __restrict__ Sv,
                                                     int* __restrict__ bar) {
  int i = blockIdx.x * 512 + threadIdx.x;      // 98*12*64 = 75264 chunks of 8 halfs
  if (i < 75264) {
    int nt = i / 768;
    int rem = i - nt * 768;
    int f = rem >> 6;
    int l = rem & 63;
    int row = nt * 16 + (l & 15);
    int k = f * 32 + ((l >> 4) << 3);
    f16x8 o;
    if (row < 1560) {
      const float* s = rw + (long)row * 385 + k;
#pragma unroll
      for (int e = 0; e < 8; ++e) o[e] = (f16)s[e];
    } else {
#pragma unroll
      for (int e = 0; e < 8; ++e) o[e] = (f16)0.0f;
    }
    *(f16x8*)(RWp + (long)i * 8) = o;
  }
  if (i < 1664)
    Sv[i] = (i < 1560) ? (rw[(long)i * 385 + 384] + kw[(long)i * 4097 + 4096]) : 0.0f;
  if (i < 256) bar[i] = 0;
}

// conv_w (384,384,10) -> Wc2_f16[o][j*384+h]
__global__ __launch_bounds__(256) void k_prep_wc(const float* __restrict__ cw,
                                                 f16* __restrict__ Wc2) {
  int i = blockIdx.x * 256 + threadIdx.x;     // 384*3840
  if (i >= 384 * 3840) return;
  int o = i / 3840;
  int c = i - o * 3840;
  int j = c / 384;
  int h = c - j * 384;
  Wc2[i] = (f16)cw[((long)o * 384 + h) * 10 + j];
}

// scale_w (64,384)->swp(128,384,f16,zero-pad rows); scale_b->sbp(128); rescale_w(384,64)->rwp2(384,128,zero-pad cols)
__global__ __launch_bounds__(256) void k_prep_scale(const float* __restrict__ sw,
                                                    const float* __restrict__ sb,
                                                    const float* __restrict__ rw2,
                                                    f16* __restrict__ swp,
                                                    float* __restrict__ sbp,
                                                    f16* __restrict__ rwp2) {
  int i = blockIdx.x * 256 + threadIdx.x;   // 49152
  if (i < 128 * 384) {
    int o = i / 384, k = i - o * 384;
    swp[i] = (f16)((o < 64) ? sw[o * 384 + k] : 0.0f);
    int o2 = i >> 7, k2 = i & 127;
    rwp2[i] = (f16)((k2 < 64) ? rw2[o2 * 64 + k2] : 0.0f);
  }
  if (i < 128) sbp[i] = (i < 64) ? sb[i] : 0.0f;
}

// generic fp32 -> f16 convert
__global__ __launch_bounds__(256) void k_cvt(const float* __restrict__ src,
                                             f16* __restrict__ dst, long n) {
  long i = (long)blockIdx.x * 256 + threadIdx.x;
  if (i < n) dst[i] = (f16)src[i];
}

// C = A(M x K) * W(N x K)^T (+bias[col]); m97-style global_load_lds staging.
// grid.z splits K (kLen MUST be a multiple of 32; writes partials at z*M*N).
// act: 0=f32, 1=f16, 2=relu->f16, 3=sigmoid->f32.
__global__ __launch_bounds__(256) void k_gemm_bt(const f16* __restrict__ A,
                                                 const f16* __restrict__ W,
                                                 void* __restrict__ Cv,
                                                 const float* __restrict__ bias,
                                                 int N, int K, int kLen, int act) {
  __shared__ __align__(16) f16 As[128 * 32];   // unpadded: global_load_lds needs lane-contiguous dest
  __shared__ __align__(16) f16 Bs[128 * 32];
  const int tid = threadIdx.x;
  const long rowA0 = (long)blockIdx.x * 128;
  const long rowB0 = (long)blockIdx.y * 128;
  const long ks = (long)blockIdx.z * kLen;
  const long zoff = (long)blockIdx.z * ((long)gridDim.x * 128 * N);
  const int w = tid >> 6, lane = tid & 63;
  const int q = lane >> 4, r16 = lane & 15;
  const int wr = w >> 1, wc = w & 1;
  f32x4 acc[4][4] = {};
  const int srow = tid >> 2;
  const int scol = (tid & 3) * 8;
  const f16* gA0 = A + (rowA0 + srow) * (long)K + ks + scol;
  const f16* gA1 = gA0 + 64L * K;
  const f16* gB0 = W + (rowB0 + srow) * (long)K + ks + scol;
  const f16* gB1 = gB0 + 64L * K;
  f16* lA = As + tid * 8;
  f16* lB = Bs + tid * 8;
  for (int k0 = 0; k0 < kLen; k0 += 32) {
    __syncthreads();
    gld16(gA0 + k0, lA);
    gld16(gA1 + k0, lA + 2048);
    gld16(gB0 + k0, lB);
    gld16(gB1 + k0, lB + 2048);
    __syncthreads();
    f16x8 af[4], bfr[4];
#pragma unroll
    for (int i = 0; i < 4; i++) {
      af[i]  = *(const f16x8*)&As[(wr * 64 + i * 16 + r16) * 32 + q * 8];
      bfr[i] = *(const f16x8*)&Bs[(wc * 64 + i * 16 + r16) * 32 + q * 8];
    }
#pragma unroll
    for (int i = 0; i < 4; i++)
#pragma unroll
      for (int j = 0; j < 4; j++)
        acc[i][j] = __builtin_amdgcn_mfma_f32_16x16x32_f16(af[i], bfr[j], acc[i][j], 0, 0, 0);
  }
#pragma unroll
  for (int i = 0; i < 4; i++)
#pragma unroll
    for (int j = 0; j < 4; j++) {
      long row = rowA0 + wr * 64 + i * 16 + q * 4;
      long col = rowB0 + wc * 64 + j * 16 + r16;
      float bv = bias ? bias[col] : 0.0f;
#pragma unroll
      for (int r = 0; r < 4; r++) {
        float v = acc[i][j][r] + bv;
        long off = (row + r) * (long)N + col + zoff;
        if (act == 0)      ((float*)Cv)[off] = v;
        else if (act == 1) ((f16*)Cv)[off]   = (f16)v;
        else if (act == 2) ((f16*)Cv)[off]   = (f16)fmaxf(v, 0.0f);
        else               ((float*)Cv)[off] = sigm(v);
      }
    }
}

// XCD-group weights-stationary recurrence: 64 blocks = 8 groups x 8 members.
// Group g (blocks {g, g+8, ..., g+56} — same XCD under round-robin dispatch) owns
// batches [32g, 32g+32) and holds ALL of RW in LDS across its members (12-13
// tiles each, ~156 KB dynamic LDS, loaded once). Batches are independent across
// groups -> sync is ONLY the 8-member group barrier, twice per step.
__global__ __launch_bounds__(512)
void k_recur_coop(const f16* __restrict__ XKh,    // (12800,1664) f16, bias folded
                  const f16* __restrict__ RWp,    // packed (98,12,64,8) f16
                  const float* __restrict__ Sv,   // (1664)
                  const float* __restrict__ timep,// (256,50)
                  f16* __restrict__ xo_g,         // (256, XOG)
                  f16* __restrict__ hext_g,       // (256, 384)
                  float* __restrict__ h_all,      // (50,256,384)
                  float* __restrict__ dists,      // (50,256)
                  int* __restrict__ bar) {
  extern __shared__ char smem[];
  f16*   Wl  = (f16*)smem;                        // up to 13 tiles x 6144 halfs
  float* Svl = (float*)(smem + 159744);           // up to 13*16 floats
  const int tid = threadIdx.x;
  const int g   = blockIdx.x & 7;                 // group (XCD under round-robin)
  const int m   = blockIdx.x >> 3;                // member 0..7
  const int b0  = g * 32;                         // group batch base
  const int T      = (m < 2) ? 13 : 12;           // 2*13 + 6*12 = 98 tiles
  const int tstart = (m < 2) ? m * 13 : 26 + (m - 2) * 12;
  int* gb_bar = bar + 32 * g;
  const int w = tid >> 6, lane = tid & 63;
  const int q = lane >> 4, r16 = lane & 15;
  // stationary weights + Sv slice -> LDS (once)
  {
    const f16* src = RWp + (size_t)tstart * 6144;
    for (int i = tid; i < T * 768; i += 512)
      *(f16x8*)(Wl + (size_t)i * 8) = *(const f16x8*)(src + (size_t)i * 8);
    for (int i = tid; i < T * 16; i += 512) Svl[i] = Sv[tstart * 16 + i];
  }
  // zero this member's 4 hext rows
  {
    f16x8 z = {};
    for (int i = tid; i < 192; i += 512) {
      int row = b0 + m * 4 + (i / 48);
      *(f16x8*)(hext_g + (size_t)row * 384 + (i % 48) * 8) = z;
    }
  }
  gbar(gb_bar, NMEM);

  // gate mapping: thread = (batch gm 0..3, l-quarter lq 0..3, channel gch 0..31)
  const int gm = tid >> 7;
  const int lq = (tid >> 5) & 3;
  const int gch = tid & 31;
  const int gb = b0 + m * 4 + gm;
  float creg[3] = {};

  for (int t = 0; t < 50; ++t) {
    // ---- GEMM phase: wave w -> M-tile (w&1), N-tiles j = (w>>1) + 4k ----
    const int mi = w & 1;
    const int rowb = b0 + mi * 16;
    f16x8 af[12];
    const f16* ab = hext_g + (size_t)(rowb + r16) * 384 + q * 8;
#pragma unroll
    for (int f = 0; f < 12; ++f) af[f] = *(const f16x8*)(ab + f * 32);
    float tv4[4];
#pragma unroll
    for (int r = 0; r < 4; ++r) tv4[r] = timep[(rowb + q * 4 + r) * 50 + t];
    for (int j = (w >> 1); j < T; j += 4) {
      const int c0 = (tstart + j) * 16;
      f16 xk[4];
#pragma unroll
      for (int r = 0; r < 4; ++r)
        xk[r] = XKh[((long)(rowb + q * 4 + r) * 50 + t) * GP + c0 + r16];
      const f16* bp = Wl + (size_t)j * 6144 + lane * 8;
      f32x4 a0 = {};
#pragma unroll
      for (int f = 0; f < 12; ++f)
        a0 = __builtin_amdgcn_mfma_f32_16x16x32_f16(af[f], *(const f16x8*)(bp + f * 512), a0, 0, 0, 0);
      const float Svc = Svl[j * 16 + r16];
#pragma unroll
      for (int r = 0; r < 4; ++r)
        xo_g[(size_t)(rowb + q * 4 + r) * XOG + c0 + r16] = (f16)(a0[r] + (float)xk[r] + tv4[r] * Svc);
    }
    gbar(gb_bar, NMEM);   // group's xo ready
    // ---- gate phase: 4 batches per member ----
    {
      const f16* xom = xo_g + (size_t)gb * XOG;
      float fm[12], im[12];
      {
        float v1[12], v2[12], mx1 = -1e30f, mx2 = -1e30f;
#pragma unroll
        for (int l = 0; l < 12; l++) {
          v1[l] = (float)xom[l];      mx1 = fmaxf(mx1, v1[l]);
          v2[l] = (float)xom[12 + l]; mx2 = fmaxf(mx2, v2[l]);
        }
        float s1 = 0.0f, s2 = 0.0f;
#pragma unroll
        for (int l = 0; l < 12; l++) {
          v1[l] = __expf(v1[l] - mx1); s1 += v1[l];
          v2[l] = __expf(v2[l] - mx2); s2 += v2[l];
        }
        float i1 = 1.0f / s1, i2 = 1.0f / s2, c1 = 0.0f, c2 = 0.0f;
#pragma unroll
        for (int l = 0; l < 12; l++) { c1 += v1[l]; fm[l] = c1 * i1; }
#pragma unroll
        for (int l = 11; l >= 0; l--) { c2 += v2[l]; im[l] = c2 * i2; }
      }
      if (lq == 0 && gch == 0) {
        float ds = 0.0f;
#pragma unroll
        for (int l = 0; l < 12; l++) ds += fm[l];
        dists[t * 256 + gb] = 1.0f - ds * (1.0f / 12.0f);
      }
      float* hdst = h_all + ((long)t * 256 + gb) * 384;
#pragma unroll
      for (int jj = 0; jj < 3; jj++) {
        const int l = lq * 3 + jj;
        float fv = sigm((float)xom[24 + l * 32 + gch]);
        float iv = sigm((float)xom[24 + (12 + l) * 32 + gch]);
        float og = sigm((float)xom[24 + (24 + l) * 32 + gch]);
        float ci = tanhfast((float)xom[24 + (36 + l) * 32 + gch]);
        float fmv = fm[l], imv = im[l], ov = fmv * imv;
        float cn = ov * (fv * creg[jj] + iv * ci) + (fmv - ov) * creg[jj] + (imv - ov) * ci;
        creg[jj] = cn;
        float hv = og * tanhfast(cn);
        hdst[l * 32 + gch] = hv;
        hext_g[(size_t)gb * 384 + l * 32 + gch] = (f16)hv;
      }
    }
    gbar(gb_bar, NMEM);   // group's hext(t) visible for GEMM(t+1)
  }
}

// ld[b,t,:] = softmax_j(cumsum_j dist[t-9+j])
__global__ __launch_bounds__(256) void k_ld(const float* __restrict__ dists,
                                            float* __restrict__ ld) {
  int i = blockIdx.x * 256 + threadIdx.x;
  if (i >= 12800) return;
  int b = i / 50, t = i - b * 50;
  float v[10];
  float cum = 0.0f, mx = -1e30f;
#pragma unroll
  for (int j = 0; j < 10; j++) {
    int s = t - 9 + j;
    float d = (s >= 0) ? dists[s * 256 + b] : 0.0f;
    cum += d; v[j] = cum; mx = fmaxf(mx, cum);
  }
  float sum = 0.0f;
#pragma unroll
  for (int j = 0; j < 10; j++) { v[j] = __expf(v[j] - mx); sum += v[j]; }
  float inv = 1.0f / sum;
#pragma unroll
  for (int j = 0; j < 10; j++) ld[i * 10 + j] = v[j] * inv;
}

// lh_f16[(b,t)][j*384+h] = ld[b,t,j] * h_{t-9+j}[b,h]
__global__ __launch_bounds__(256) void k_lh(const float* __restrict__ ld,
                                            const float* __restrict__ h_all,
                                            f16* __restrict__ lh) {
  int i = blockIdx.x * 256 + threadIdx.x;   // 12800*480
  int row = i / 480;
  int c = i - row * 480;
  int j = c / 48;
  int h0 = (c - j * 48) * 8;
  int b = row / 50, t = row - b * 50;
  int s = t - 9 + j;
  f16x8 o;
  if (s >= 0) {
    float wv = ld[row * 10 + j];
    const float* hp = h_all + ((long)s * 256 + b) * 384 + h0;
#pragma unroll
    for (int k = 0; k < 8; k++) o[k] = (f16)(wv * hp[k]);
  } else {
#pragma unroll
    for (int k = 0; k < 8; k++) o[k] = (f16)0.0f;
  }
  *(f16x8*)(lh + (long)row * KH + j * 384 + h0) = o;
}

// mlh_h[(b,t)][h] = mean_j (f16)
__global__ __launch_bounds__(256) void k_mlh(const float* __restrict__ ld,
                                             const float* __restrict__ h_all,
                                             f16* __restrict__ mlh) {
  int i = blockIdx.x * 256 + threadIdx.x;   // 12800*384
  int row = i / 384, h = i - row * 384;
  int b = row / 50, t = row - b * 50;
  float acc = 0.0f;
#pragma unroll
  for (int j = 0; j < 10; j++) {
    int s = t - 9 + j;
    if (s >= 0) acc += ld[row * 10 + j] * h_all[((long)s * 256 + b) * 384 + h];
  }
  mlh[i] = (f16)(acc * 0.1f);
}

// rnn_f16[b][t*384+h] = theme*(conv0+conv1+conv_b) + h
__global__ __launch_bounds__(256) void k_rnn(const float* __restrict__ theme,
                                             const float* __restrict__ convp,  // 2 partials
                                             const float* __restrict__ cb,
                                             const float* __restrict__ h_all,
                                             f16* __restrict__ rnn) {
  int i = blockIdx.x * 256 + threadIdx.x;   // 12800*384, ordered (b,t,h)
  int row = i / 384, h = i - row * 384;
  int b = row / 50, t = row - b * 50;
  float conv = convp[i] + convp[4915200 + i] + cb[h];
  float local = theme[i] * conv;
  float hv = h_all[((long)t * 256 + b) * 384 + h];
  rnn[i] = (f16)(local + hv);               // (b*50+t)*384+h == b*19200 + t*384 + h
}

// out[i] = sum_z part[z][i] + out_b
__global__ __launch_bounds__(256) void k_red8(const float* __restrict__ part,
                                              const float* __restrict__ ob,
                                              float* __restrict__ out) {
  int i = blockIdx.x * 256 + threadIdx.x;   // 32768
  float s = 0.0f;
#pragma unroll
  for (int z = 0; z < 8; z++) s += part[z * 32768 + i];
  out[i] = s + ob[i & 127];
}

// ---------------- launch ----------------
extern "C" void kernel_launch(void* const* d_in, const int* in_sizes, int n_in,
                              void* d_out, int out_size, void* d_ws, size_t ws_size,
                              hipStream_t stream) {
  (void)in_sizes; (void)n_in; (void)out_size; (void)ws_size;
  const int*   node_ids  = (const int*)  d_in[0];
  const float* timep     = (const float*)d_in[3];
  const float* embed     = (const float*)d_in[6];
  const float* kernel_w  = (const float*)d_in[7];
  const float* kernel_b  = (const float*)d_in[8];
  const float* rec_w     = (const float*)d_in[9];
  const float* rec_b     = (const float*)d_in[10];
  const float* scale_w   = (const float*)d_in[11];
  const float* scale_b   = (const float*)d_in[12];
  const float* rescale_w = (const float*)d_in[13];
  const float* rescale_b = (const float*)d_in[14];
  const float* conv_w    = (const float*)d_in[15];
  const float* conv_b    = (const float*)d_in[16];
  const float* out_w     = (const float*)d_in[17];
  const float* out_b     = (const float*)d_in[18];

  char* ws = (char*)d_ws;
  f16*   xf      = (f16*)  (ws + OFF_X);
  f16*   lh      = (f16*)  (ws + OFF_LH);
  float* opart   = (float*)(ws + OFF_OPART);
  f16*   xo_g    = (f16*)  (ws + OFF_XOG);
  f16*   hext_g  = (f16*)  (ws + OFF_HEXT);
  f16*   Wk      = (f16*)  (ws + OFF_WK);
  f16*   XKh     = (f16*)  (ws + OFF_XK);
  f16*   mlh_h   = (f16*)  (ws + OFF_MLH);
  f16*   s1h     = (f16*)  (ws + OFF_S1);
  float* theme   = (float*)(ws + OFF_TH);
  float* convbuf = (float*)(ws + OFF_CV);
  f16*   swp     = (f16*)  (ws + OFF_SWP);
  f16*   rwp2    = (f16*)  (ws + OFF_RWP2);
  float* sbp     = (float*)(ws + OFF_SBP);
  f16*   RWp     = (f16*)  (ws + OFF_RW);
  float* Sv      = (float*)(ws + OFF_SV);
  int*   bar     = (int*)  (ws + OFF_BAR);
  float* biasc   = (float*)(ws + OFF_BIASC);
  float* h_all   = (float*)(ws + OFF_HALL);
  float* ldbuf   = (float*)(ws + OFF_LD);
  f16*   Wc2     = (f16*)  (ws + OFF_WC2);
  f16*   rnn     = (f16*)  (ws + OFF_RNN);
  f16*   outw    = (f16*)  (ws + OFF_OUTW);

  float* outp  = (float*)d_out;          // (256,128)
  float* dists = outp + 256 * 128;       // (50,256)

  // phase 0: prep
  k_gather     <<<25600, 256, 0, stream>>>(node_ids, embed, xf);
  k_prep_wk    <<<26624, 256, 0, stream>>>(kernel_w, kernel_b, rec_b, Wk, biasc);
  k_prep_rwpack<<<147,   512, 0, stream>>>(rec_w, kernel_w, RWp, Sv, bar);
  k_prep_scale <<<192,   256, 0, stream>>>(scale_w, scale_b, rescale_w, swp, sbp, rwp2);
  k_prep_wc    <<<5760,  256, 0, stream>>>(conv_w, Wc2);
  // phase 1: XKh = f16( x @ kernel_w^T + (kernel_b + rec_b) )
  k_gemm_bt<<<dim3(100, 13), 256, 0, stream>>>(xf, Wk, XKh, biasc, GP, 4096, 4096, 1);
  // phase 2: XCD-group weights-stationary recurrence
  {
    hipFuncSetAttribute((const void*)k_recur_coop,
                        hipFuncAttributeMaxDynamicSharedMemorySize, RECUR_LDS);
    void* cargs[] = {(void*)&XKh, (void*)&RWp, (void*)&Sv, (void*)&timep,
                     (void*)&xo_g, (void*)&hext_g, (void*)&h_all, (void*)&dists,
                     (void*)&bar};
    hipLaunchCooperativeKernel((void*)k_recur_coop, dim3(NGRP * NMEM), dim3(512),
                               cargs, RECUR_LDS, stream);
  }
  // phase 3: deferred outputs (fully parallel)
  k_ld  <<<50,    256, 0, stream>>>(dists, ldbuf);
  k_lh  <<<24000, 256, 0, stream>>>(ldbuf, h_all, lh);
  k_mlh <<<19200, 256, 0, stream>>>(ldbuf, h_all, mlh_h);
  k_gemm_bt<<<dim3(100, 1), 256, 0, stream>>>(mlh_h, swp, s1h, sbp, 128, 384, 384, 2);
  k_gemm_bt<<<dim3(100, 3), 256, 0, stream>>>(s1h, rwp2, theme, rescale_b, 384, 128, 128, 3);
  k_gemm_bt<<<dim3(100, 3, 2), 256, 0, stream>>>(lh, Wc2, convbuf, nullptr, 384, KH, KH / 2, 0);
  k_rnn <<<19200, 256, 0, stream>>>(theme, convbuf, conv_b, h_all, rnn);
  k_cvt <<<9600,  256, 0, stream>>>(out_w, outw, 128L * KO);
  // phase 4: out = rnn @ out_w^T + out_b   (K split 8 ways: 2400 = 75*32, exact)
  k_gemm_bt<<<dim3(2, 1, 8), 256, 0, stream>>>(rnn, outw, opart, nullptr, 128, KO, KO / 8, 0);
  k_red8<<<128, 256, 0, stream>>>(opart, out_b, outp);
}

// Round 10
// 1308.720 us; speedup vs baseline: 2.0584x; 1.0540x over previous
//
#include <hip/hip_runtime.h>
#include <math.h>

// ---------------- types ----------------
typedef _Float16 f16;
typedef _Float16 f16x8 __attribute__((ext_vector_type(8)));
typedef float f32x4 __attribute__((ext_vector_type(4)));

#define DEV static __device__ __forceinline__

DEV float sigm(float x)  { return 1.0f / (1.0f + __expf(-x)); }
DEV float tanhfast(float x) { return 2.0f / (1.0f + __expf(-2.0f * x)) - 1.0f; }

// async global->LDS, 16B per lane (dest must be wave-uniform base + lane*16)
DEV void gld16(const void* g, void* l) {
  __builtin_amdgcn_global_load_lds((const __attribute__((address_space(1))) void*)g,
                                   (__attribute__((address_space(3))) void*)l, 16, 0, 0);
}

// minimal-fence group barrier (proven in R9): release rides the arrival RMW,
// spin is RELAXED (no per-poll L2 inv), single ACQUIRE load on exit.
DEV void gbar(int* bar, int nblk) {
  __syncthreads();
  if (threadIdx.x == 0) {
    int* cnt = bar;
    int* gen = bar + 16;
    int g = __hip_atomic_load(gen, __ATOMIC_RELAXED, __HIP_MEMORY_SCOPE_AGENT);
    int a = __hip_atomic_fetch_add(cnt, 1, __ATOMIC_RELEASE, __HIP_MEMORY_SCOPE_AGENT);
    if (a == nblk - 1) {
      __hip_atomic_store(cnt, 0, __ATOMIC_RELAXED, __HIP_MEMORY_SCOPE_AGENT);
      __hip_atomic_store(gen, g + 1, __ATOMIC_RELEASE, __HIP_MEMORY_SCOPE_AGENT);
    } else {
      while (__hip_atomic_load(gen, __ATOMIC_RELAXED, __HIP_MEMORY_SCOPE_AGENT) == g)
        __builtin_amdgcn_s_sleep(1);
    }
    (void)__hip_atomic_load(gen, __ATOMIC_ACQUIRE, __HIP_MEMORY_SCOPE_AGENT); // single inv
  }
  __syncthreads();
}

// ---------------- problem constants ----------------
// B=256 V=50 N=32 D=128 H=384 L=12 CS=10 ND=4096 G=1560 OUT=128
#define GP 1664   // padded G (13*128) — XK gemm N and XKh row stride
#define KH 3840   // H*CS (conv gemm K)
#define KO 19200  // V*H  (out gemm K)
// recurrence: 8 groups (32 batches each) x 12 members (member m owns gate-group l=m)
#define NGRP 8
#define NMEM 12
#define NBLK 96
#define XOLS 164  // xo local (LDS) row stride in f32
// dyn LDS: Wl 10 tiles x 12288 B + xol 32x164 f32 + colmap 160 i32 + Svl 160 f32
#define RECUR_LDS (122880 + 20992 + 640 + 640)   // 145152

// ---------------- workspace layout (bytes) ----------------
static constexpr size_t OFF_X     = 0;                       // xf 104857600; lh/opart alias later
static constexpr size_t OFF_LH    = 0;
static constexpr size_t OFF_OPART = 0;                       // out partials 8*32768*4
static constexpr size_t OFF_ZB    = 1048576;                 // zero h buffer f16 256*384*2 = 196608 (xf alias)
static constexpr size_t OFF_WK    = 104857600;               // 13631488
static constexpr size_t OFF_XK    = OFF_WK + 13631488;       // XKh f16 12800*1664*2 = 42598400
// aliases of the XK region (XKh dead after k_recur):
static constexpr size_t OFF_MLH   = OFF_XK;                  // mlh_h f16 9830400
static constexpr size_t OFF_S1    = OFF_XK + 9830400;        // s1h f16 3276800
static constexpr size_t OFF_TH    = OFF_XK + 13107200;       // theme f32 19660800
static constexpr size_t OFF_CV    = OFF_XK + 32768000;       // conv partials 2x19660800 (ends +72089600)
static constexpr size_t OFF_SWP   = OFF_XK + 72089600;       // swp f16 98304 (> XKh end)
static constexpr size_t OFF_RWP2  = OFF_XK + 72187904;       // rwp2 f16 98304
static constexpr size_t OFF_SBP   = OFF_XK + 72286208;       // sbp f32 512
static constexpr size_t OFF_RW    = OFF_XK + 85196800;       // RWpack f16 12*10*12288 = 1474560
static constexpr size_t OFF_SV    = OFF_RW + 1474560;        // Sv f32 6656 (pad 8192)
static constexpr size_t OFF_BAR   = OFF_SV + 8192;           // barrier state 8 groups x 32 ints
static constexpr size_t OFF_BIASC = OFF_BAR + 4096;          // 8192
static constexpr size_t OFF_HALL  = OFF_BIASC + 8192;        // h_all f16 50*256*384*2 = 9830400
static constexpr size_t OFF_LD    = OFF_HALL + 9830400;      // 512000
static constexpr size_t OFF_WC2   = OFF_LD + 512000;         // 2949120
static constexpr size_t OFF_RNN   = OFF_WC2 + 2949120;       // 9830400
static constexpr size_t OFF_OUTW  = OFF_RNN + 9830400;       // 4915200

// ---------------- kernels ----------------

// embedding gather -> x_f16 (12800 x 4096), 8 halfs / thread
__global__ __launch_bounds__(256) void k_gather(const int* __restrict__ ids,
                                                const float* __restrict__ embed,
                                                f16* __restrict__ xf) {
  int i = blockIdx.x * 256 + threadIdx.x;     // 12800*512 total
  int row = i >> 9;
  int c8  = i & 511;
  int n = c8 >> 4;
  int d = (c8 & 15) << 3;
  int id = ids[row * 32 + n];
  const float* e = embed + (long)id * 128 + d;
  float4 a = *(const float4*)e;
  float4 b = *(const float4*)(e + 4);
  f16x8 o;
  o[0]=(f16)a.x; o[1]=(f16)a.y; o[2]=(f16)a.z; o[3]=(f16)a.w;
  o[4]=(f16)b.x; o[5]=(f16)b.y; o[6]=(f16)b.z; o[7]=(f16)b.w;
  *(f16x8*)(xf + ((long)row << 12) + (c8 << 3)) = o;
}

// kernel_w (1560 x 4097) -> Wk_f16 (1664 x 4096, zero-padded rows); biasc = kb+rb (padded 1664)
__global__ __launch_bounds__(256) void k_prep_wk(const float* __restrict__ kw,
                                                 const float* __restrict__ kb,
                                                 const float* __restrict__ rb,
                                                 f16* __restrict__ Wk,
                                                 float* __restrict__ biasc) {
  long i = (long)blockIdx.x * 256 + threadIdx.x;
  if (i < 1664L * 4096) {
    int nn = (int)(i >> 12);
    int k  = (int)(i & 4095);
    float v = (nn < 1560) ? kw[(long)nn * 4097 + k] : 0.0f;
    Wk[i] = (f16)v;
  }
  if (i < 1664) biasc[i] = (i < 1560) ? (kb[i] + rb[i]) : 0.0f;
}

// rec_w (1560x385) -> member-packed RWp: RWp[m][tile τ<10][f<12][lane<64][e<8].
// Member m local col lc = τ*16+(lane&15): lc<24 -> orig col lc (fm/im logits,
// replicated to every member); 24<=lc<32 -> zero pad; lc>=32 -> gate run
// run=(lc-32)/32 (f,i,o,cin), orig col = 24 + (run*12+m)*32 + (lc-32)%32.
// k = f*32 + (lane>>4)*8 + e.  Also Sv and barrier-state init.
__global__ __launch_bounds__(512) void k_prep_rwpack(const float* __restrict__ rw,
                                                     const float* __restrict__ kw,
                                                     f16* __restrict__ RWp,
                                                     float* __restrict__ Sv,
                                                     int* __restrict__ bar) {
  int i = blockIdx.x * 512 + threadIdx.x;      // 12*10*12*64 = 92160 chunks of 8 halfs
  if (i < 92160) {
    int p = i / 7680;
    int rem = i - p * 7680;
    int tau = rem / 768;
    int r2 = rem - tau * 768;
    int f = r2 >> 6;
    int l = r2 & 63;
    int lc = tau * 16 + (l & 15);
    int n;
    if (lc < 24) n = lc;
    else if (lc < 32) n = -1;
    else { int run = (lc - 32) >> 5; n = 24 + (run * 12 + p) * 32 + ((lc - 32) & 31); }
    int k = f * 32 + ((l >> 4) << 3);
    f16x8 o;
    if (n >= 0) {
      const float* s = rw + (long)n * 385 + k;
#pragma unroll
      for (int e = 0; e < 8; ++e) o[e] = (f16)s[e];
    } else {
#pragma unroll
      for (int e = 0; e < 8; ++e) o[e] = (f16)0.0f;
    }
    *(f16x8*)(RWp + (long)i * 8) = o;
  }
  if (i < 1664)
    Sv[i] = (i < 1560) ? (rw[(long)i * 385 + 384] + kw[(long)i * 4097 + 4096]) : 0.0f;
  if (i < 256) bar[i] = 0;
}

// conv_w (384,384,10) -> Wc2_f16[o][j*384+h]
__global__ __launch_bounds__(256) void k_prep_wc(const float* __restrict__ cw,
                                                 f16* __restrict__ Wc2) {
  int i = blockIdx.x * 256 + threadIdx.x;     // 384*3840
  if (i >= 384 * 3840) return;
  int o = i / 3840;
  int c = i - o * 3840;
  int j = c / 384;
  int h = c - j * 384;
  Wc2[i] = (f16)cw[((long)o * 384 + h) * 10 + j];
}

// scale_w (64,384)->swp(128,384,f16,zero-pad rows); scale_b->sbp(128); rescale_w(384,64)->rwp2(384,128,zero-pad cols)
__global__ __launch_bounds__(256) void k_prep_scale(const float* __restrict__ sw,
                                                    const float* __restrict__ sb,
                                                    const float* __restrict__ rw2,
                                                    f16* __restrict__ swp,
                                                    float* __restrict__ sbp,
                                                    f16* __restrict__ rwp2) {
  int i = blockIdx.x * 256 + threadIdx.x;   // 49152
  if (i < 128 * 384) {
    int o = i / 384, k = i - o * 384;
    swp[i] = (f16)((o < 64) ? sw[o * 384 + k] : 0.0f);
    int o2 = i >> 7, k2 = i & 127;
    rwp2[i] = (f16)((k2 < 64) ? rw2[o2 * 64 + k2] : 0.0f);
  }
  if (i < 128) sbp[i] = (i < 64) ? sb[i] : 0.0f;
}

// generic fp32 -> f16 convert
__global__ __launch_bounds__(256) void k_cvt(const float* __restrict__ src,
                                             f16* __restrict__ dst, long n) {
  long i = (long)blockIdx.x * 256 + threadIdx.x;
  if (i < n) dst[i] = (f16)src[i];
}

// C = A(M x K) * W(N x K)^T (+bias[col]); m97-style global_load_lds staging.
// grid.z splits K (kLen MUST be a multiple of 32; partials at z*M*N).
// act: 0=f32, 1=f16, 2=relu->f16, 3=sigmoid->f32.
__global__ __launch_bounds__(256) void k_gemm_bt(const f16* __restrict__ A,
                                                 const f16* __restrict__ W,
                                                 void* __restrict__ Cv,
                                                 const float* __restrict__ bias,
                                                 int N, int K, int kLen, int act) {
  __shared__ __align__(16) f16 As[128 * 32];   // unpadded: global_load_lds needs lane-contiguous dest
  __shared__ __align__(16) f16 Bs[128 * 32];
  const int tid = threadIdx.x;
  const long rowA0 = (long)blockIdx.x * 128;
  const long rowB0 = (long)blockIdx.y * 128;
  const long ks = (long)blockIdx.z * kLen;
  const long zoff = (long)blockIdx.z * ((long)gridDim.x * 128 * N);
  const int w = tid >> 6, lane = tid & 63;
  const int q = lane >> 4, r16 = lane & 15;
  const int wr = w >> 1, wc = w & 1;
  f32x4 acc[4][4] = {};
  const int srow = tid >> 2;
  const int scol = (tid & 3) * 8;
  const f16* gA0 = A + (rowA0 + srow) * (long)K + ks + scol;
  const f16* gA1 = gA0 + 64L * K;
  const f16* gB0 = W + (rowB0 + srow) * (long)K + ks + scol;
  const f16* gB1 = gB0 + 64L * K;
  f16* lA = As + tid * 8;
  f16* lB = Bs + tid * 8;
  for (int k0 = 0; k0 < kLen; k0 += 32) {
    __syncthreads();
    gld16(gA0 + k0, lA);
    gld16(gA1 + k0, lA + 2048);
    gld16(gB0 + k0, lB);
    gld16(gB1 + k0, lB + 2048);
    __syncthreads();
    f16x8 af[4], bfr[4];
#pragma unroll
    for (int i = 0; i < 4; i++) {
      af[i]  = *(const f16x8*)&As[(wr * 64 + i * 16 + r16) * 32 + q * 8];
      bfr[i] = *(const f16x8*)&Bs[(wc * 64 + i * 16 + r16) * 32 + q * 8];
    }
#pragma unroll
    for (int i = 0; i < 4; i++)
#pragma unroll
      for (int j = 0; j < 4; j++)
        acc[i][j] = __builtin_amdgcn_mfma_f32_16x16x32_f16(af[i], bfr[j], acc[i][j], 0, 0, 0);
  }
#pragma unroll
  for (int i = 0; i < 4; i++)
#pragma unroll
    for (int j = 0; j < 4; j++) {
      long row = rowA0 + wr * 64 + i * 16 + q * 4;
      long col = rowB0 + wc * 64 + j * 16 + r16;
      float bv = bias ? bias[col] : 0.0f;
#pragma unroll
      for (int r = 0; r < 4; r++) {
        float v = acc[i][j][r] + bv;
        long off = (row + r) * (long)N + col + zoff;
        if (act == 0)      ((float*)Cv)[off] = v;
        else if (act == 1) ((f16*)Cv)[off]   = (f16)v;
        else if (act == 2) ((f16*)Cv)[off]   = (f16)fmaxf(v, 0.0f);
        else               ((float*)Cv)[off] = sigm(v);
      }
    }
}

// gate-partitioned weights-stationary recurrence: 96 blocks = 8 groups x 12 members.
// Group owns 32 batches; member m owns gate-group l=m. Member weights (10 packed
// tiles: 24 shared fm/im cols replicated + its 128 gate cols) live in LDS. xo is
// BLOCK-LOCAL (LDS fp32) — never goes to global. Only h(t) is communicated:
// ONE group barrier per step. GEMM(t) reads h(t-1) from h_all (f16), zbuf at t=0.
__global__ __launch_bounds__(512)
void k_recur_coop(const f16* __restrict__ XKh,    // (12800,1664) f16, bias folded
                  const f16* __restrict__ RWp,    // member-packed (12,10,12,64,8) f16
                  const float* __restrict__ Sv,   // (1664)
                  const float* __restrict__ timep,// (256,50)
                  f16* __restrict__ zbuf,         // (256,384) zeroed here
                  f16* __restrict__ hall,         // (50,256,384) f16
                  float* __restrict__ dists,      // (50,256)
                  int* __restrict__ bar) {
  extern __shared__ char smem[];
  f16*   Wl     = (f16*)smem;                     // 10 tiles x 6144 halfs
  float* xol    = (float*)(smem + 122880);        // 32 x XOLS
  int*   colmap = (int*)(smem + 143872);          // 160
  float* Svl    = (float*)(smem + 144512);        // 160
  const int tid = threadIdx.x;
  const int g = blockIdx.x / NMEM;
  const int m = blockIdx.x - g * NMEM;            // this member's l
  const int b0 = g * 32;
  int* gbbar = bar + 32 * g;
  const int w = tid >> 6, lane = tid & 63;
  const int q = lane >> 4, r16 = lane & 15;
  // stationary member weights -> LDS (once)
  {
    const f16* src = RWp + (size_t)m * 61440;
    for (int i = tid; i < 7680; i += 512)
      *(f16x8*)(Wl + (size_t)i * 8) = *(const f16x8*)(src + (size_t)i * 8);
  }
  if (tid < 160) {
    int lc = tid, n;
    if (lc < 24) n = lc;
    else if (lc < 32) n = -1;
    else { int run = (lc - 32) >> 5; n = 24 + (run * 12 + m) * 32 + ((lc - 32) & 31); }
    colmap[lc] = n;
    Svl[lc] = (n >= 0) ? Sv[n] : 0.0f;
  }
  // zero the group's 32 zbuf rows (split across members; only m<3 have work)
  {
    f16x8 z = {};
    for (int i = m * 512 + tid; i < 1536; i += NMEM * 512)
      *(f16x8*)(zbuf + (size_t)b0 * 384 + (size_t)i * 8) = z;
  }
  gbar(gbbar, NMEM);

  const int ch = tid & 31, bloc = tid >> 5;       // bloc 0..15; batches bloc, bloc+16
  float creg[2] = {0.0f, 0.0f};

  for (int t = 0; t < 50; ++t) {
    // ---- GEMM: wave w -> M-tile (w&1), local N-tiles j = (w>>1) + 4k < 10 ----
    const f16* hprev = (t == 0) ? zbuf : (hall + (size_t)(t - 1) * 98304);
    const int mi = w & 1;
    const int rowb = b0 + mi * 16;
    f16x8 af[12];
    const f16* ab = hprev + (size_t)(rowb + r16) * 384 + q * 8;
#pragma unroll
    for (int f = 0; f < 12; ++f) af[f] = *(const f16x8*)(ab + f * 32);
    float tv4[4];
#pragma unroll
    for (int r = 0; r < 4; ++r) tv4[r] = timep[(rowb + q * 4 + r) * 50 + t];
    for (int j = (w >> 1); j < 10; j += 4) {
      const f16* bp = Wl + (size_t)j * 6144 + lane * 8;
      f32x4 a0 = {};
#pragma unroll
      for (int f = 0; f < 12; ++f)
        a0 = __builtin_amdgcn_mfma_f32_16x16x32_f16(af[f], *(const f16x8*)(bp + f * 512), a0, 0, 0, 0);
      const int lc = j * 16 + r16;
      const int n = colmap[lc];
      const float Svc = Svl[lc];
#pragma unroll
      for (int r = 0; r < 4; ++r) {
        float xk = 0.0f;
        if (n >= 0) xk = (float)XKh[((long)(rowb + q * 4 + r) * 50 + t) * GP + n];
        xol[(mi * 16 + q * 4 + r) * XOLS + lc] = a0[r] + xk + tv4[r] * Svc;
      }
    }
    __syncthreads();   // xol ready (block-local)
    // ---- gates for l=m: thread -> (ch, batches bloc & bloc+16) ----
#pragma unroll
    for (int half = 0; half < 2; ++half) {
      const int b = bloc + half * 16;
      const int gb = b0 + b;
      const float* xr = xol + b * XOLS;
      float e1[12], e2[12], mx1 = -1e30f, mx2 = -1e30f;
#pragma unroll
      for (int l = 0; l < 12; ++l) {
        e1[l] = xr[l];      mx1 = fmaxf(mx1, e1[l]);
        e2[l] = xr[12 + l]; mx2 = fmaxf(mx2, e2[l]);
      }
      float s1 = 0.0f, s2 = 0.0f;
#pragma unroll
      for (int l = 0; l < 12; ++l) {
        e1[l] = __expf(e1[l] - mx1); s1 += e1[l];
        e2[l] = __expf(e2[l] - mx2); s2 += e2[l];
      }
      float cum1 = 0.0f;
      for (int l = 0; l <= m; ++l) cum1 += e1[l];
      const float fmv = cum1 / s1;
      float cum2 = 0.0f;
      for (int l = 11; l >= m; --l) cum2 += e2[l];
      const float imv = cum2 / s2;
      if (m == 0 && ch == 0) {
        float ds = 0.0f;
#pragma unroll
        for (int l = 0; l < 12; ++l) ds += (float)(12 - l) * e1[l];
        dists[t * 256 + gb] = 1.0f - ds / (12.0f * s1);
      }
      const float fv = sigm(xr[32 + ch]);
      const float iv = sigm(xr[64 + ch]);
      const float og = sigm(xr[96 + ch]);
      const float ci = tanhfast(xr[128 + ch]);
      const float ov = fmv * imv;
      const float cn = ov * (fv * creg[half] + iv * ci) + (fmv - ov) * creg[half] + (imv - ov) * ci;
      creg[half] = cn;
      const float hv = og * tanhfast(cn);
      hall[((size_t)t * 256 + gb) * 384 + m * 32 + ch] = (f16)hv;
    }
    gbar(gbbar, NMEM);   // h(t) visible group-wide for GEMM(t+1); also guards xol reuse
  }
}

// ld[b,t,:] = softmax_j(cumsum_j dist[t-9+j])
__global__ __launch_bounds__(256) void k_ld(const float* __restrict__ dists,
                                            float* __restrict__ ld) {
  int i = blockIdx.x * 256 + threadIdx.x;
  if (i >= 12800) return;
  int b = i / 50, t = i - b * 50;
  float v[10];
  float cum = 0.0f, mx = -1e30f;
#pragma unroll
  for (int j = 0; j < 10; j++) {
    int s = t - 9 + j;
    float d = (s >= 0) ? dists[s * 256 + b] : 0.0f;
    cum += d; v[j] = cum; mx = fmaxf(mx, cum);
  }
  float sum = 0.0f;
#pragma unroll
  for (int j = 0; j < 10; j++) { v[j] = __expf(v[j] - mx); sum += v[j]; }
  float inv = 1.0f / sum;
#pragma unroll
  for (int j = 0; j < 10; j++) ld[i * 10 + j] = v[j] * inv;
}

// lh_f16[(b,t)][j*384+h] = ld[b,t,j] * h_{t-9+j}[b,h]   (h_all is f16)
__global__ __launch_bounds__(256) void k_lh(const float* __restrict__ ld,
                                            const f16* __restrict__ h_all,
                                            f16* __restrict__ lh) {
  int i = blockIdx.x * 256 + threadIdx.x;   // 12800*480
  int row = i / 480;
  int c = i - row * 480;
  int j = c / 48;
  int h0 = (c - j * 48) * 8;
  int b = row / 50, t = row - b * 50;
  int s = t - 9 + j;
  f16x8 o;
  if (s >= 0) {
    float wv = ld[row * 10 + j];
    f16x8 hv8 = *(const f16x8*)(h_all + ((size_t)s * 256 + b) * 384 + h0);
#pragma unroll
    for (int k = 0; k < 8; k++) o[k] = (f16)(wv * (float)hv8[k]);
  } else {
#pragma unroll
    for (int k = 0; k < 8; k++) o[k] = (f16)0.0f;
  }
  *(f16x8*)(lh + (long)row * KH + j * 384 + h0) = o;
}

// mlh_h[(b,t)][h] = mean_j
__global__ __launch_bounds__(256) void k_mlh(const float* __restrict__ ld,
                                             const f16* __restrict__ h_all,
                                             f16* __restrict__ mlh) {
  int i = blockIdx.x * 256 + threadIdx.x;   // 12800*384
  int row = i / 384, h = i - row * 384;
  int b = row / 50, t = row - b * 50;
  float acc = 0.0f;
#pragma unroll
  for (int j = 0; j < 10; j++) {
    int s = t - 9 + j;
    if (s >= 0) acc += ld[row * 10 + j] * (float)h_all[((size_t)s * 256 + b) * 384 + h];
  }
  mlh[i] = (f16)(acc * 0.1f);
}

// rnn_f16[b][t*384+h] = theme*(conv0+conv1+conv_b) + h
__global__ __launch_bounds__(256) void k_rnn(const float* __restrict__ theme,
                                             const float* __restrict__ convp,  // 2 partials
                                             const float* __restrict__ cb,
                                             const f16* __restrict__ h_all,
                                             f16* __restrict__ rnn) {
  int i = blockIdx.x * 256 + threadIdx.x;   // 12800*384, ordered (b,t,h)
  int row = i / 384, h = i - row * 384;
  int b = row / 50, t = row - b * 50;
  float conv = convp[i] + convp[4915200 + i] + cb[h];
  float local = theme[i] * conv;
  float hv = (float)h_all[((size_t)t * 256 + b) * 384 + h];
  rnn[i] = (f16)(local + hv);               // (b*50+t)*384+h == b*19200 + t*384 + h
}

// out[i] = sum_z part[z][i] + out_b
__global__ __launch_bounds__(256) void k_red8(const float* __restrict__ part,
                                              const float* __restrict__ ob,
                                              float* __restrict__ out) {
  int i = blockIdx.x * 256 + threadIdx.x;   // 32768
  float s = 0.0f;
#pragma unroll
  for (int z = 0; z < 8; z++) s += part[z * 32768 + i];
  out[i] = s + ob[i & 127];
}

// ---------------- launch ----------------
extern "C" void kernel_launch(void* const* d_in, const int* in_sizes, int n_in,
                              void* d_out, int out_size, void* d_ws, size_t ws_size,
                              hipStream_t stream) {
  (void)in_sizes; (void)n_in; (void)out_size; (void)ws_size;
  const int*   node_ids  = (const int*)  d_in[0];
  const float* timep     = (const float*)d_in[3];
  const float* embed     = (const float*)d_in[6];
  const float* kernel_w  = (const float*)d_in[7];
  const float* kernel_b  = (const float*)d_in[8];
  const float* rec_w     = (const float*)d_in[9];
  const float* rec_b     = (const float*)d_in[10];
  const float* scale_w   = (const float*)d_in[11];
  const float* scale_b   = (const float*)d_in[12];
  const float* rescale_w = (const float*)d_in[13];
  const float* rescale_b = (const float*)d_in[14];
  const float* conv_w    = (const float*)d_in[15];
  const float* conv_b    = (const float*)d_in[16];
  const float* out_w     = (const float*)d_in[17];
  const float* out_b     = (const float*)d_in[18];

  char* ws = (char*)d_ws;
  f16*   xf      = (f16*)  (ws + OFF_X);
  f16*   lh      = (f16*)  (ws + OFF_LH);
  float* opart   = (float*)(ws + OFF_OPART);
  f16*   zbuf    = (f16*)  (ws + OFF_ZB);
  f16*   Wk      = (f16*)  (ws + OFF_WK);
  f16*   XKh     = (f16*)  (ws + OFF_XK);
  f16*   mlh_h   = (f16*)  (ws + OFF_MLH);
  f16*   s1h     = (f16*)  (ws + OFF_S1);
  float* theme   = (float*)(ws + OFF_TH);
  float* convbuf = (float*)(ws + OFF_CV);
  f16*   swp     = (f16*)  (ws + OFF_SWP);
  f16*   rwp2    = (f16*)  (ws + OFF_RWP2);
  float* sbp     = (float*)(ws + OFF_SBP);
  f16*   RWp     = (f16*)  (ws + OFF_RW);
  float* Sv      = (float*)(ws + OFF_SV);
  int*   bar     = (int*)  (ws + OFF_BAR);
  float* biasc   = (float*)(ws + OFF_BIASC);
  f16*   h_all   = (f16*)  (ws + OFF_HALL);
  float* ldbuf   = (float*)(ws + OFF_LD);
  f16*   Wc2     = (f16*)  (ws + OFF_WC2);
  f16*   rnn     = (f16*)  (ws + OFF_RNN);
  f16*   outw    = (f16*)  (ws + OFF_OUTW);

  float* outp  = (float*)d_out;          // (256,128)
  float* dists = outp + 256 * 128;       // (50,256)

  // phase 0: prep
  k_gather     <<<25600, 256, 0, stream>>>(node_ids, embed, xf);
  k_prep_wk    <<<26624, 256, 0, stream>>>(kernel_w, kernel_b, rec_b, Wk, biasc);
  k_prep_rwpack<<<180,   512, 0, stream>>>(rec_w, kernel_w, RWp, Sv, bar);
  k_prep_scale <<<192,   256, 0, stream>>>(scale_w, scale_b, rescale_w, swp, sbp, rwp2);
  k_prep_wc    <<<5760,  256, 0, stream>>>(conv_w, Wc2);
  // phase 1: XKh = f16( x @ kernel_w^T + (kernel_b + rec_b) )
  k_gemm_bt<<<dim3(100, 13), 256, 0, stream>>>(xf, Wk, XKh, biasc, GP, 4096, 4096, 1);
  // phase 2: gate-partitioned weights-stationary recurrence (1 barrier/step)
  {
    hipFuncSetAttribute((const void*)k_recur_coop,
                        hipFuncAttributeMaxDynamicSharedMemorySize, RECUR_LDS);
    void* cargs[] = {(void*)&XKh, (void*)&RWp, (void*)&Sv, (void*)&timep,
                     (void*)&zbuf, (void*)&h_all, (void*)&dists, (void*)&bar};
    hipLaunchCooperativeKernel((void*)k_recur_coop, dim3(NBLK), dim3(512),
                               cargs, RECUR_LDS, stream);
  }
  // phase 3: deferred outputs (fully parallel)
  k_ld  <<<50,    256, 0, stream>>>(dists, ldbuf);
  k_lh  <<<24000, 256, 0, stream>>>(ldbuf, h_all, lh);
  k_mlh <<<19200, 256, 0, stream>>>(ldbuf, h_all, mlh_h);
  k_gemm_bt<<<dim3(100, 1), 256, 0, stream>>>(mlh_h, swp, s1h, sbp, 128, 384, 384, 2);
  k_gemm_bt<<<dim3(100, 3), 256, 0, stream>>>(s1h, rwp2, theme, rescale_b, 384, 128, 128, 3);
  k_gemm_bt<<<dim3(100, 3, 2), 256, 0, stream>>>(lh, Wc2, convbuf, nullptr, 384, KH, KH / 2, 0);
  k_rnn <<<19200, 256, 0, stream>>>(theme, convbuf, conv_b, h_all, rnn);
  k_cvt <<<9600,  256, 0, stream>>>(out_w, outw, 128L * KO);
  // phase 4: out = rnn @ out_w^T + out_b   (K split 8 ways: 2400 = 75*32, exact)
  k_gemm_bt<<<dim3(2, 1, 8), 256, 0, stream>>>(rnn, outw, opart, nullptr, 128, KO, KO / 8, 0);
  k_red8<<<128, 256, 0, stream>>>(opart, out_b, outp);
}